// Round 3
// baseline (110.924 us; speedup 1.0000x reference)
//
#include <hip/hip_runtime.h>
#include <stdint.h>

typedef __bf16 bf16x8 __attribute__((ext_vector_type(8)));
typedef float f32x4 __attribute__((ext_vector_type(4)));

// ---------------------------------------------------------------------------
// async global->LDS 16B
__device__ __forceinline__ void gload16(const void* g, void* l) {
  __builtin_amdgcn_global_load_lds((const __attribute__((address_space(1))) void*)g,
                                   (__attribute__((address_space(3))) void*)l,
                                   16, 0, 0);
}

// ---------------------------------------------------------------------------
// pair-row mapping for the padded 36864-row layer-2 matrix
//  rows [0,4096):   SS region, 128 groups (g=b*2+w) x 32 rows (30 valid)
//  rows [4096,...): SQ region, 2048 groups (h=(b*16+q)*2+wv) x 16 rows (12 valid)
__device__ __forceinline__ void maprow(int gr, int& rowU, int& rowV, bool& ok) {
  if (gr < 4096) {
    int g = gr >> 5, p = gr & 31;
    ok = (p < 30);
    int i = p / 5, jj = p % 5;
    int j = jj + (jj >= i);
    rowU = g * 6 + j;
    rowV = g * 6 + i;
  } else {
    int r2 = gr - 4096;
    int h = r2 >> 4, p = r2 & 15;
    ok = (p < 12);
    int b = h >> 5, q = (h >> 1) & 15, wv = h & 1;
    int sbase = (b * 2 + wv) * 6;
    int qrow = 768 + b * 16 + q;
    if (p < 6) { rowU = qrow; rowV = sbase + p; }
    else       { rowU = sbase + (p - 6); rowV = qrow; }
  }
  if (!ok) { rowU = 0; rowV = 0; }
}

// ---------------------------------------------------------------------------
// Kernel 1: converts + transposes into bf16 working buffers
__global__ void convert_all(const float* __restrict__ xs, const float* __restrict__ xq,
                            const float* __restrict__ Wg1, const float* __restrict__ Wg2,
                            const float* __restrict__ Wf1,
                            __bf16* __restrict__ Xb, __bf16* __restrict__ Wg1T,
                            __bf16* __restrict__ Wg2T, __bf16* __restrict__ Wf1T) {
  int e = blockIdx.x * 256 + threadIdx.x;
  if (e < 917504) {
    int row = e >> 9, k = e & 511;
    float v = (row < 768) ? xs[row * 512 + k] : xq[(row - 768) * 512 + k];
    Xb[e] = (__bf16)v;
  } else if (e < 1441792) {
    int e2 = e - 917504;
    int c = e2 >> 9, k = e2 & 511;
    float v = (c < 512) ? Wg1[k * 512 + c] : Wg1[(512 + k) * 512 + (c - 512)];
    Wg1T[e2] = (__bf16)v;
  } else if (e < 1703936) {
    int e2 = e - 1441792;
    int n = e2 >> 9, k = e2 & 511;
    Wg2T[e2] = (__bf16)Wg2[k * 512 + n];
  } else {
    int e2 = e - 1703936;
    int c = e2 >> 9, k = e2 & 511;
    Wf1T[e2] = (__bf16)Wf1[k * 512 + c];
  }
}

// ---------------------------------------------------------------------------
// Generic 128x128-tile bf16 MFMA GEMM, C = A(MxK) * BT(NxK)^T, fp32 accum.
//  EPI 0: store raw fp32 C ;  EPI 1: store relu(C + bias[col])
template <int EPI>
__global__ __launch_bounds__(256) void gemm128(const __bf16* __restrict__ A,
                                               const __bf16* __restrict__ BT,
                                               float* __restrict__ C,
                                               const float* __restrict__ bias,
                                               int M, int N, int K) {
  __shared__ __align__(16) char smem[16384];
  __bf16* As = (__bf16*)smem;
  __bf16* Bs = (__bf16*)(smem + 8192);

  int bid = blockIdx.x;
  {
    int nwg = gridDim.x;
    if ((nwg & 7) == 0) { int q = nwg >> 3; bid = (bid & 7) * q + (bid >> 3); }
  }
  const int ntn = N >> 7;
  const int tm = bid / ntn;
  const int tn = bid % ntn;

  const int t = threadIdx.x;
  const int w = t >> 6, l = t & 63;
  const int wm = (w >> 1) << 6;
  const int wn = (w & 1) << 6;
  const int lr = l & 15, lg = l >> 4;

  const int arow0 = t >> 2;
  const int kch = (((t & 3) ^ ((t >> 4) & 3)) * 8);
  const __bf16* Ag  = A + (size_t)(tm * 128 + arow0) * K + kch;
  const __bf16* Ag2 = Ag + (size_t)64 * K;
  const __bf16* Bg  = BT + (size_t)(tn * 128 + arow0) * K + kch;
  const __bf16* Bg2 = Bg + (size_t)64 * K;
  char* lA  = smem + t * 16;
  char* lA2 = smem + 4096 + t * 16;
  char* lB  = smem + 8192 + t * 16;
  char* lB2 = smem + 8192 + 4096 + t * 16;

  f32x4 acc[4][4];
#pragma unroll
  for (int m = 0; m < 4; m++)
#pragma unroll
    for (int n = 0; n < 4; n++) acc[m][n] = (f32x4){0.f, 0.f, 0.f, 0.f};

  const int rchunk = (lg ^ (lr >> 2)) * 8;

  for (int k0 = 0; k0 < K; k0 += 32) {
    gload16(Ag + k0, lA);
    gload16(Ag2 + k0, lA2);
    gload16(Bg + k0, lB);
    gload16(Bg2 + k0, lB2);
    asm volatile("s_waitcnt vmcnt(0)" ::: "memory");
    __syncthreads();

    bf16x8 fa[4], fb[4];
#pragma unroll
    for (int m = 0; m < 4; m++)
      fa[m] = *(const bf16x8*)(As + (wm + m * 16 + lr) * 32 + rchunk);
#pragma unroll
    for (int n = 0; n < 4; n++)
      fb[n] = *(const bf16x8*)(Bs + (wn + n * 16 + lr) * 32 + rchunk);
#pragma unroll
    for (int m = 0; m < 4; m++)
#pragma unroll
      for (int n = 0; n < 4; n++)
        acc[m][n] = __builtin_amdgcn_mfma_f32_16x16x32_bf16(fa[m], fb[n], acc[m][n], 0, 0, 0);
    __syncthreads();
  }

#pragma unroll
  for (int m = 0; m < 4; m++)
#pragma unroll
    for (int n = 0; n < 4; n++) {
      int col = tn * 128 + wn + n * 16 + lr;
#pragma unroll
      for (int reg = 0; reg < 4; reg++) {
        int row = tm * 128 + wm + m * 16 + lg * 4 + reg;
        float v = acc[m][n][reg];
        if (EPI == 1) v = fmaxf(v + bias[col], 0.0f);
        C[(size_t)row * N + col] = v;
      }
    }
}

// ---------------------------------------------------------------------------
// Fused layer-2: A rows built on the fly from UV (relu(U+V+bg1) -> bf16),
// B = Wg2T staged via global_load_lds. Output strip 128x256 per block
// (4 waves of 64x128). Epilogue: relu(+bg2) + per-group row reduce.
__global__ __launch_bounds__(256, 2) void gemm2_fused(
    const float* __restrict__ UV, const float* __restrict__ bg1,
    const __bf16* __restrict__ BT, const float* __restrict__ bias,
    float* __restrict__ outSS, float* __restrict__ outSQ) {
  __shared__ __align__(16) char smem[8192 + 16384];
  __bf16* As = (__bf16*)smem;            // [128][32], chunk-swizzled
  __bf16* Bs = (__bf16*)(smem + 8192);   // [256][32], chunk-swizzled

  int bid = blockIdx.x;
  { int q = gridDim.x >> 3; bid = (bid & 7) * q + (bid >> 3); }  // 576 % 8 == 0
  const int tm = bid >> 1;     // 0..287 row tile
  const int tnp = bid & 1;     // col half (256 cols)

  const int t = threadIdx.x;
  const int w = t >> 6, l = t & 63;
  const int wm = (w >> 1) << 6;     // 0/64
  const int wn = (w & 1) << 7;      // 0/128
  const int lr = l & 15, lg = l >> 4;

  // A-staging: thread owns rows rl0=t>>2, rl1=rl0+64; source chunk c=t&3
  const int rl0 = t >> 2;
  const int c = t & 3;
  const int wchunk = c ^ ((rl0 >> 2) & 3);   // same for rl0 and rl0+64
  int rowU0, rowV0, rowU1, rowV1;
  bool ok0, ok1;
  maprow(tm * 128 + rl0, rowU0, rowV0, ok0);
  maprow(tm * 128 + rl0 + 64, rowU1, rowV1, ok1);
  const float* u0p = UV + (size_t)rowU0 * 1024 + c * 8;
  const float* v0p = UV + (size_t)rowV0 * 1024 + 512 + c * 8;
  const float* u1p = UV + (size_t)rowU1 * 1024 + c * 8;
  const float* v1p = UV + (size_t)rowV1 * 1024 + 512 + c * 8;
  __bf16* wA0 = As + rl0 * 32 + wchunk * 8;
  __bf16* wA1 = As + (rl0 + 64) * 32 + wchunk * 8;

  // B-staging via gload16: 4 rows (rl0 + 0/64/128/192), linear LDS dest,
  // source chunk inverse-swizzled
  const int kch = (((t & 3) ^ ((t >> 4) & 3)) * 8);
  const __bf16* Bg = BT + (size_t)(tnp * 256 + rl0) * 512 + kch;
  char* lB = smem + 8192 + t * 16;

  f32x4 acc[4][8];
#pragma unroll
  for (int m = 0; m < 4; m++)
#pragma unroll
    for (int n = 0; n < 8; n++) acc[m][n] = (f32x4){0.f, 0.f, 0.f, 0.f};

  const int rchunk = (lg ^ (lr >> 2)) * 8;

  for (int k0 = 0; k0 < 512; k0 += 32) {
    // issue B async loads first
    gload16(Bg + k0, lB);
    gload16(Bg + (size_t)64 * 512 + k0, lB + 4096);
    gload16(Bg + (size_t)128 * 512 + k0, lB + 8192);
    gload16(Bg + (size_t)192 * 512 + k0, lB + 12288);

    // build A rows from UV
    const float4* bgp = (const float4*)(bg1 + k0 + c * 8);
    float4 bb0 = bgp[0], bb1 = bgp[1];
    {
      bf16x8 o;
      if (ok0) {
        float4 a0 = *(const float4*)(u0p + k0), a1 = *(const float4*)(u0p + k0 + 4);
        float4 e0 = *(const float4*)(v0p + k0), e1 = *(const float4*)(v0p + k0 + 4);
        o[0] = (__bf16)fmaxf(a0.x + e0.x + bb0.x, 0.0f);
        o[1] = (__bf16)fmaxf(a0.y + e0.y + bb0.y, 0.0f);
        o[2] = (__bf16)fmaxf(a0.z + e0.z + bb0.z, 0.0f);
        o[3] = (__bf16)fmaxf(a0.w + e0.w + bb0.w, 0.0f);
        o[4] = (__bf16)fmaxf(a1.x + e1.x + bb1.x, 0.0f);
        o[5] = (__bf16)fmaxf(a1.y + e1.y + bb1.y, 0.0f);
        o[6] = (__bf16)fmaxf(a1.z + e1.z + bb1.z, 0.0f);
        o[7] = (__bf16)fmaxf(a1.w + e1.w + bb1.w, 0.0f);
      } else {
#pragma unroll
        for (int e = 0; e < 8; e++) o[e] = (__bf16)0.0f;
      }
      *(bf16x8*)(wA0) = o;
    }
    {
      bf16x8 o;
      if (ok1) {
        float4 a0 = *(const float4*)(u1p + k0), a1 = *(const float4*)(u1p + k0 + 4);
        float4 e0 = *(const float4*)(v1p + k0), e1 = *(const float4*)(v1p + k0 + 4);
        o[0] = (__bf16)fmaxf(a0.x + e0.x + bb0.x, 0.0f);
        o[1] = (__bf16)fmaxf(a0.y + e0.y + bb0.y, 0.0f);
        o[2] = (__bf16)fmaxf(a0.z + e0.z + bb0.z, 0.0f);
        o[3] = (__bf16)fmaxf(a0.w + e0.w + bb0.w, 0.0f);
        o[4] = (__bf16)fmaxf(a1.x + e1.x + bb1.x, 0.0f);
        o[5] = (__bf16)fmaxf(a1.y + e1.y + bb1.y, 0.0f);
        o[6] = (__bf16)fmaxf(a1.z + e1.z + bb1.z, 0.0f);
        o[7] = (__bf16)fmaxf(a1.w + e1.w + bb1.w, 0.0f);
      } else {
#pragma unroll
        for (int e = 0; e < 8; e++) o[e] = (__bf16)0.0f;
      }
      *(bf16x8*)(wA1) = o;
    }

    asm volatile("s_waitcnt vmcnt(0)" ::: "memory");
    __syncthreads();

    bf16x8 fa[4], fb[8];
#pragma unroll
    for (int m = 0; m < 4; m++)
      fa[m] = *(const bf16x8*)(As + (wm + m * 16 + lr) * 32 + rchunk);
#pragma unroll
    for (int n = 0; n < 8; n++)
      fb[n] = *(const bf16x8*)(Bs + (wn + n * 16 + lr) * 32 + rchunk);
#pragma unroll
    for (int m = 0; m < 4; m++)
#pragma unroll
      for (int n = 0; n < 8; n++)
        acc[m][n] = __builtin_amdgcn_mfma_f32_16x16x32_bf16(fa[m], fb[n], acc[m][n], 0, 0, 0);
    __syncthreads();
  }

  // epilogue: relu(+bias) in-register, group reduce via shfl
  if (tm < 32) {
    // SS: 4 groups x 32 rows (30 valid; pad rows in odd-m frags at lg*4+reg>=14)
#pragma unroll
    for (int pair = 0; pair < 2; pair++) {
#pragma unroll
      for (int n = 0; n < 8; n++) {
        int col = tnp * 256 + wn + n * 16 + lr;
        float bv = bias[col];
        float s = 0.0f;
#pragma unroll
        for (int mh = 0; mh < 2; mh++) {
          int m = pair * 2 + mh;
#pragma unroll
          for (int reg = 0; reg < 4; reg++) {
            bool ok = (mh == 0) || (lg * 4 + reg < 14);
            float v = fmaxf(acc[m][n][reg] + bv, 0.0f);
            s += ok ? v : 0.0f;
          }
        }
        s += __shfl_xor(s, 16);
        s += __shfl_xor(s, 32);
        if (l < 16) {
          int g = (wm >> 5) + pair;
          outSS[(size_t)(tm * 4 + g) * 512 + col] = s;
        }
      }
    }
  } else {
    // SQ: 8 groups x 16 rows (12 valid; lg==3 pad)
#pragma unroll
    for (int m = 0; m < 4; m++) {
#pragma unroll
      for (int n = 0; n < 8; n++) {
        int col = tnp * 256 + wn + n * 16 + lr;
        float bv = bias[col];
        float s = 0.0f;
#pragma unroll
        for (int reg = 0; reg < 4; reg++) {
          float v = fmaxf(acc[m][n][reg] + bv, 0.0f);
          s += (lg < 3) ? v : 0.0f;
        }
        s += __shfl_xor(s, 16);
        s += __shfl_xor(s, 32);
        if (l < 16) {
          int h = (tm - 32) * 8 + (wm >> 4) + m;
          outSQ[(size_t)h * 512 + col] = s;
        }
      }
    }
  }
}

// ---------------------------------------------------------------------------
// Fused layer-3: A rows = bf16(SS[ssrow]+SQ[gr]) built on the fly;
// B = Wf1T via gload16; epilogue relu(+bf1) -> H. M=2048,N=512,K=512.
__global__ __launch_bounds__(256) void gemm3_fused(
    const float* __restrict__ SS, const float* __restrict__ SQ,
    const __bf16* __restrict__ BT, const float* __restrict__ bias,
    float* __restrict__ H) {
  __shared__ __align__(16) char smem[16384];
  __bf16* As = (__bf16*)smem;
  __bf16* Bs = (__bf16*)(smem + 8192);

  int bid = blockIdx.x;
  { int q = gridDim.x >> 3; bid = (bid & 7) * q + (bid >> 3); }  // 64 % 8 == 0
  const int tm = bid >> 2;
  const int tn = bid & 3;

  const int t = threadIdx.x;
  const int w = t >> 6, l = t & 63;
  const int wm = (w >> 1) << 6;
  const int wn = (w & 1) << 6;
  const int lr = l & 15, lg = l >> 4;

  const int rl0 = t >> 2;
  const int c = t & 3;
  const int wchunk = c ^ ((rl0 >> 2) & 3);
  const int gr0 = tm * 128 + rl0, gr1 = gr0 + 64;
  const int ss0 = (gr0 >> 5) * 2 + (gr0 & 1);
  const int ss1 = (gr1 >> 5) * 2 + (gr1 & 1);
  const float* s0p = SS + (size_t)ss0 * 512 + c * 8;
  const float* q0p = SQ + (size_t)gr0 * 512 + c * 8;
  const float* s1p = SS + (size_t)ss1 * 512 + c * 8;
  const float* q1p = SQ + (size_t)gr1 * 512 + c * 8;
  __bf16* wA0 = As + rl0 * 32 + wchunk * 8;
  __bf16* wA1 = As + (rl0 + 64) * 32 + wchunk * 8;

  const int kch = (((t & 3) ^ ((t >> 4) & 3)) * 8);
  const __bf16* Bg  = BT + (size_t)(tn * 128 + rl0) * 512 + kch;
  char* lB  = smem + 8192 + t * 16;

  f32x4 acc[4][4];
#pragma unroll
  for (int m = 0; m < 4; m++)
#pragma unroll
    for (int n = 0; n < 4; n++) acc[m][n] = (f32x4){0.f, 0.f, 0.f, 0.f};

  const int rchunk = (lg ^ (lr >> 2)) * 8;

  for (int k0 = 0; k0 < 512; k0 += 32) {
    gload16(Bg + k0, lB);
    gload16(Bg + (size_t)64 * 512 + k0, lB + 4096);

    {
      float4 a0 = *(const float4*)(s0p + k0), a1 = *(const float4*)(s0p + k0 + 4);
      float4 e0 = *(const float4*)(q0p + k0), e1 = *(const float4*)(q0p + k0 + 4);
      bf16x8 o;
      o[0] = (__bf16)(a0.x + e0.x); o[1] = (__bf16)(a0.y + e0.y);
      o[2] = (__bf16)(a0.z + e0.z); o[3] = (__bf16)(a0.w + e0.w);
      o[4] = (__bf16)(a1.x + e1.x); o[5] = (__bf16)(a1.y + e1.y);
      o[6] = (__bf16)(a1.z + e1.z); o[7] = (__bf16)(a1.w + e1.w);
      *(bf16x8*)(wA0) = o;
    }
    {
      float4 a0 = *(const float4*)(s1p + k0), a1 = *(const float4*)(s1p + k0 + 4);
      float4 e0 = *(const float4*)(q1p + k0), e1 = *(const float4*)(q1p + k0 + 4);
      bf16x8 o;
      o[0] = (__bf16)(a0.x + e0.x); o[1] = (__bf16)(a0.y + e0.y);
      o[2] = (__bf16)(a0.z + e0.z); o[3] = (__bf16)(a0.w + e0.w);
      o[4] = (__bf16)(a1.x + e1.x); o[5] = (__bf16)(a1.y + e1.y);
      o[6] = (__bf16)(a1.z + e1.z); o[7] = (__bf16)(a1.w + e1.w);
      *(bf16x8*)(wA1) = o;
    }

    asm volatile("s_waitcnt vmcnt(0)" ::: "memory");
    __syncthreads();

    bf16x8 fa[4], fb[4];
#pragma unroll
    for (int m = 0; m < 4; m++)
      fa[m] = *(const bf16x8*)(As + (wm + m * 16 + lr) * 32 + rchunk);
#pragma unroll
    for (int n = 0; n < 4; n++)
      fb[n] = *(const bf16x8*)(Bs + (wn + n * 16 + lr) * 32 + rchunk);
#pragma unroll
    for (int m = 0; m < 4; m++)
#pragma unroll
      for (int n = 0; n < 4; n++)
        acc[m][n] = __builtin_amdgcn_mfma_f32_16x16x32_bf16(fa[m], fb[n], acc[m][n], 0, 0, 0);
    __syncthreads();
  }

#pragma unroll
  for (int m = 0; m < 4; m++)
#pragma unroll
    for (int n = 0; n < 4; n++) {
      int col = tn * 128 + wn + n * 16 + lr;
#pragma unroll
      for (int reg = 0; reg < 4; reg++) {
        int row = tm * 128 + wm + m * 16 + lg * 4 + reg;
        H[(size_t)row * 512 + col] = fmaxf(acc[m][n][reg] + bias[col], 0.0f);
      }
    }
}

// ---------------------------------------------------------------------------
// logits: one wave per row
__global__ void final_dot(const float* __restrict__ h, const float* __restrict__ Wf2,
                          const float* __restrict__ bf2, float* __restrict__ out) {
  int row = blockIdx.x * 4 + (threadIdx.x >> 6);
  int l = threadIdx.x & 63;
  const float4* hp = (const float4*)(h + (size_t)row * 512);
  const float4* wp = (const float4*)Wf2;
  float s = 0.0f;
#pragma unroll
  for (int i = 0; i < 2; i++) {
    float4 a = hp[l + 64 * i];
    float4 b = wp[l + 64 * i];
    s += a.x * b.x + a.y * b.y + a.z * b.z + a.w * b.w;
  }
#pragma unroll
  for (int off = 32; off; off >>= 1) s += __shfl_down(s, off, 64);
  if (l == 0) out[row] = s + bf2[0];
}

// ---------------------------------------------------------------------------
extern "C" void kernel_launch(void* const* d_in, const int* in_sizes, int n_in,
                              void* d_out, int out_size, void* d_ws, size_t ws_size,
                              hipStream_t stream) {
  const float* xs  = (const float*)d_in[0];
  const float* xq  = (const float*)d_in[1];
  const float* Wg1 = (const float*)d_in[2];
  const float* bg1 = (const float*)d_in[3];
  const float* Wg2 = (const float*)d_in[4];
  const float* bg2 = (const float*)d_in[5];
  const float* Wf1 = (const float*)d_in[6];
  const float* bf1 = (const float*)d_in[7];
  const float* Wf2 = (const float*)d_in[8];
  const float* bf2 = (const float*)d_in[9];
  float* out = (float*)d_out;

  char* ws = (char*)d_ws;
  float*  UV   = (float*)(ws);              // 1792*1024*4 = 7,340,032
  __bf16* Xb   = (__bf16*)(ws + 7340032);   // 1,835,008
  __bf16* Wg1T = (__bf16*)(ws + 9175040);   // 1,048,576
  __bf16* Wg2T = (__bf16*)(ws + 10223616);  //   524,288
  __bf16* Wf1T = (__bf16*)(ws + 10747904);  //   524,288
  float*  SSs  = (float*)(ws + 11272192);   //   262,144
  float*  SQs  = (float*)(ws + 11534336);   // 4,194,304
  float*  Hf   = (float*)(ws + 15728640);   // 4,194,304

  convert_all<<<7680, 256, 0, stream>>>(xs, xq, Wg1, Wg2, Wf1, Xb, Wg1T, Wg2T, Wf1T);
  gemm128<0><<<112, 256, 0, stream>>>(Xb, Wg1T, UV, nullptr, 1792, 1024, 512);
  gemm2_fused<<<576, 256, 0, stream>>>(UV, bg1, Wg2T, bg2, SSs, SQs);
  gemm3_fused<<<64, 256, 0, stream>>>(SSs, SQs, Wf1T, bf1, Hf);
  final_dot<<<512, 256, 0, stream>>>(Hf, Wf2, bf2, out);
}

// Round 5
// 94.153 us; speedup vs baseline: 1.1781x; 1.1781x over previous
//
#include <hip/hip_runtime.h>
#include <stdint.h>

typedef __bf16 bf16x8 __attribute__((ext_vector_type(8)));
typedef float f32x4 __attribute__((ext_vector_type(4)));

// ---------------------------------------------------------------------------
__device__ __forceinline__ void gload16(const void* g, void* l) {
  __builtin_amdgcn_global_load_lds((const __attribute__((address_space(1))) void*)g,
                                   (__attribute__((address_space(3))) void*)l,
                                   16, 0, 0);
}

// pair-row mapping for the padded 36864-row layer-2 matrix (proven R3)
__device__ __forceinline__ void maprow(int gr, int& rowU, int& rowV, bool& ok) {
  if (gr < 4096) {
    int g = gr >> 5, p = gr & 31;
    ok = (p < 30);
    int i = p / 5, jj = p % 5;
    int j = jj + (jj >= i);
    rowU = g * 6 + j;
    rowV = g * 6 + i;
  } else {
    int r2 = gr - 4096;
    int h = r2 >> 4, p = r2 & 15;
    ok = (p < 12);
    int b = h >> 5, q = (h >> 1) & 15, wv = h & 1;
    int sbase = (b * 2 + wv) * 6;
    int qrow = 768 + b * 16 + q;
    if (p < 6) { rowU = qrow; rowV = sbase + p; }
    else       { rowU = sbase + (p - 6); rowV = qrow; }
  }
  if (!ok) { rowU = 0; rowV = 0; }
}

__device__ __forceinline__ bf16x8 cvt8(float4 a, float4 b) {
  bf16x8 o;
  o[0] = (__bf16)a.x; o[1] = (__bf16)a.y; o[2] = (__bf16)a.z; o[3] = (__bf16)a.w;
  o[4] = (__bf16)b.x; o[5] = (__bf16)b.y; o[6] = (__bf16)b.z; o[7] = (__bf16)b.w;
  return o;
}

// ---------------------------------------------------------------------------
// weight transposes -> bf16 (proven-equivalent region code)
__global__ void convert_w(const float* __restrict__ Wg1, const float* __restrict__ Wg2,
                          const float* __restrict__ Wf1,
                          __bf16* __restrict__ Wg1T, __bf16* __restrict__ Wg2T,
                          __bf16* __restrict__ Wf1T) {
  int e = blockIdx.x * 256 + threadIdx.x;
  if (e < 524288) {
    int c = e >> 9, k = e & 511;
    float v = (c < 512) ? Wg1[k * 512 + c] : Wg1[(512 + k) * 512 + (c - 512)];
    Wg1T[e] = (__bf16)v;
  } else if (e < 786432) {
    int e2 = e - 524288;
    int n = e2 >> 9, k = e2 & 511;
    Wg2T[e2] = (__bf16)Wg2[k * 512 + n];
  } else {
    int e2 = e - 786432;
    int c = e2 >> 9, k = e2 & 511;
    Wf1T[e2] = (__bf16)Wf1[k * 512 + c];
  }
}

// ---------------------------------------------------------------------------
// Layer-1: UVb[1792][1024] (bf16) = bf16(x) @ Wg1T^T.  128x128 tiles, 2x2
// waves (proven geometry), A built from xs/xq in staging, 2-phase dbuf LDS.
__global__ __launch_bounds__(256, 2) void gemm1_fused(
    const float* __restrict__ xs, const float* __restrict__ xq,
    const __bf16* __restrict__ BT, __bf16* __restrict__ UVb) {
  __shared__ __align__(16) char smem[32768];  // As[2] 8K each, Bs[2] 8K each

  int bid = blockIdx.x;
  { int nwg = gridDim.x; if ((nwg & 7) == 0) { int q = nwg >> 3; bid = (bid & 7) * q + (bid >> 3); } }
  const int tm = bid >> 3;   // 0..13
  const int tn = bid & 7;    // 0..7
  const int t = threadIdx.x, w = t >> 6, l = t & 63;
  const int wm = (w >> 1) << 6, wn = (w & 1) << 6;
  const int lr = l & 15, lg = l >> 4;

  const int rl0 = t >> 2, c = t & 3;
  const int wchunk = c ^ ((rl0 >> 2) & 3);
  const int gr0 = tm * 128 + rl0, gr1 = gr0 + 64;
  const float* x0 = ((gr0 < 768) ? xs + (size_t)gr0 * 512 : xq + (size_t)(gr0 - 768) * 512) + c * 8;
  const float* x1 = ((gr1 < 768) ? xs + (size_t)gr1 * 512 : xq + (size_t)(gr1 - 768) * 512) + c * 8;

  const int kch = ((t & 3) ^ ((t >> 4) & 3)) * 8;
  const __bf16* Bg = BT + (size_t)(tn * 128 + rl0) * 512 + kch;

  __bf16* As_base = (__bf16*)smem;             // + cur*4096 elems
  char*   Bs_base = smem + 16384;              // + cur*8192 bytes

  f32x4 acc[4][4];
#pragma unroll
  for (int m = 0; m < 4; m++)
#pragma unroll
    for (int n = 0; n < 4; n++) acc[m][n] = (f32x4){0.f, 0.f, 0.f, 0.f};
  const int rchunk = (lg ^ (lr >> 2)) * 8;

  // prologue: stage buffer 0, k0 = 0
  gload16(Bg, Bs_base + t * 16);
  gload16(Bg + (size_t)64 * 512, Bs_base + 4096 + t * 16);
  {
    float4 a0 = *(const float4*)(x0), a1 = *(const float4*)(x0 + 4);
    float4 b0 = *(const float4*)(x1), b1 = *(const float4*)(x1 + 4);
    *(bf16x8*)(As_base + rl0 * 32 + wchunk * 8) = cvt8(a0, a1);
    *(bf16x8*)(As_base + (rl0 + 64) * 32 + wchunk * 8) = cvt8(b0, b1);
  }
  __syncthreads();

  int cur = 0;
  for (int it = 0; it < 15; ++it) {
    const int nxt = cur ^ 1;
    const int kn = (it + 1) * 32;
    // issue next-tile loads (T14 split: loads early, writes late)
    gload16(Bg + kn, Bs_base + nxt * 8192 + t * 16);
    gload16(Bg + (size_t)64 * 512 + kn, Bs_base + nxt * 8192 + 4096 + t * 16);
    float4 a0 = *(const float4*)(x0 + kn), a1 = *(const float4*)(x0 + kn + 4);
    float4 b0 = *(const float4*)(x1 + kn), b1 = *(const float4*)(x1 + kn + 4);
    // compute current
    {
      __bf16* As = As_base + cur * 4096;
      __bf16* Bs = (__bf16*)(Bs_base + cur * 8192);
      bf16x8 fa[4], fb[4];
#pragma unroll
      for (int m = 0; m < 4; m++)
        fa[m] = *(const bf16x8*)(As + (wm + m * 16 + lr) * 32 + rchunk);
#pragma unroll
      for (int n = 0; n < 4; n++)
        fb[n] = *(const bf16x8*)(Bs + (wn + n * 16 + lr) * 32 + rchunk);
#pragma unroll
      for (int m = 0; m < 4; m++)
#pragma unroll
        for (int n = 0; n < 4; n++)
          acc[m][n] = __builtin_amdgcn_mfma_f32_16x16x32_bf16(fa[m], fb[n], acc[m][n], 0, 0, 0);
    }
    // write next-tile A
    *(bf16x8*)(As_base + nxt * 4096 + rl0 * 32 + wchunk * 8) = cvt8(a0, a1);
    *(bf16x8*)(As_base + nxt * 4096 + (rl0 + 64) * 32 + wchunk * 8) = cvt8(b0, b1);
    __syncthreads();
    cur = nxt;
  }
  // final compute
  {
    __bf16* As = As_base + cur * 4096;
    __bf16* Bs = (__bf16*)(Bs_base + cur * 8192);
    bf16x8 fa[4], fb[4];
#pragma unroll
    for (int m = 0; m < 4; m++)
      fa[m] = *(const bf16x8*)(As + (wm + m * 16 + lr) * 32 + rchunk);
#pragma unroll
    for (int n = 0; n < 4; n++)
      fb[n] = *(const bf16x8*)(Bs + (wn + n * 16 + lr) * 32 + rchunk);
#pragma unroll
    for (int m = 0; m < 4; m++)
#pragma unroll
      for (int n = 0; n < 4; n++)
        acc[m][n] = __builtin_amdgcn_mfma_f32_16x16x32_bf16(fa[m], fb[n], acc[m][n], 0, 0, 0);
  }

#pragma unroll
  for (int m = 0; m < 4; m++)
#pragma unroll
    for (int n = 0; n < 4; n++) {
      int col = tn * 128 + wn + n * 16 + lr;
#pragma unroll
      for (int reg = 0; reg < 4; reg++) {
        int row = tm * 128 + wm + m * 16 + lg * 4 + reg;
        UVb[(size_t)row * 1024 + col] = (__bf16)acc[m][n][reg];
      }
    }
}

// ---------------------------------------------------------------------------
// Layer-2: A rows = relu(U[rowU]+V[rowV]+bg1) built from bf16 UVb in staging
// (R3-proven mapping), B = Wg2T. 128x256 strip per block, 2x2 waves (R3
// geometry), 2-phase dbuf. Epilogue: relu(+bg2) + group row-reduce (R3 exact).
__global__ __launch_bounds__(256, 2) void gemm2_fused(
    const __bf16* __restrict__ UVb, const float* __restrict__ bg1,
    const __bf16* __restrict__ BT, const float* __restrict__ bg2,
    float* __restrict__ outSS, float* __restrict__ outSQ) {
  __shared__ __align__(16) char smem[49152];  // As[2] 8K, Bs[2] 16K

  int bid = blockIdx.x;
  { int q = gridDim.x >> 3; bid = (bid & 7) * q + (bid >> 3); }  // 576 % 8 == 0
  const int tm = bid >> 1;    // 0..287
  const int tnp = bid & 1;    // col half
  const int t = threadIdx.x, w = t >> 6, l = t & 63;
  const int wm = (w >> 1) << 6;   // 0/64
  const int wn = (w & 1) << 7;    // 0/128
  const int lr = l & 15, lg = l >> 4;

  const int rl0 = t >> 2, c = t & 3;
  const int wchunk = c ^ ((rl0 >> 2) & 3);
  int rU0, rV0, rU1, rV1; bool ok0, ok1;
  maprow(tm * 128 + rl0, rU0, rV0, ok0);
  maprow(tm * 128 + rl0 + 64, rU1, rV1, ok1);
  const __bf16* u0p = UVb + (size_t)rU0 * 1024 + c * 8;
  const __bf16* v0p = UVb + (size_t)rV0 * 1024 + 512 + c * 8;
  const __bf16* u1p = UVb + (size_t)rU1 * 1024 + c * 8;
  const __bf16* v1p = UVb + (size_t)rV1 * 1024 + 512 + c * 8;
  const float* gp = bg1 + c * 8;

  const int kch = ((t & 3) ^ ((t >> 4) & 3)) * 8;
  const __bf16* Bg = BT + (size_t)(tnp * 256 + rl0) * 512 + kch;

  __bf16* As_base = (__bf16*)smem;          // + cur*4096 elems (8 KB)
  char*   Bs_base = smem + 16384;           // + cur*16384 bytes

  f32x4 acc[4][8];
#pragma unroll
  for (int m = 0; m < 4; m++)
#pragma unroll
    for (int n = 0; n < 8; n++) acc[m][n] = (f32x4){0.f, 0.f, 0.f, 0.f};
  const int rchunk = (lg ^ (lr >> 2)) * 8;

  // A-build: o[e] = relu(f(u[e]) + f(v[e]) + bias[e]); zeroed for pad rows
#define BUILD_A(o, u, v, bl, bh, okk)                                      \
  {                                                                        \
    if (okk) {                                                             \
      o[0] = (__bf16)fmaxf((float)u[0] + (float)v[0] + bl.x, 0.f);         \
      o[1] = (__bf16)fmaxf((float)u[1] + (float)v[1] + bl.y, 0.f);         \
      o[2] = (__bf16)fmaxf((float)u[2] + (float)v[2] + bl.z, 0.f);         \
      o[3] = (__bf16)fmaxf((float)u[3] + (float)v[3] + bl.w, 0.f);         \
      o[4] = (__bf16)fmaxf((float)u[4] + (float)v[4] + bh.x, 0.f);         \
      o[5] = (__bf16)fmaxf((float)u[5] + (float)v[5] + bh.y, 0.f);         \
      o[6] = (__bf16)fmaxf((float)u[6] + (float)v[6] + bh.z, 0.f);         \
      o[7] = (__bf16)fmaxf((float)u[7] + (float)v[7] + bh.w, 0.f);         \
    } else {                                                               \
      for (int e = 0; e < 8; e++) o[e] = (__bf16)0.0f;                     \
    }                                                                      \
  }

  // prologue: stage buffer 0, k0 = 0
  gload16(Bg, Bs_base + t * 16);
  gload16(Bg + (size_t)64 * 512, Bs_base + 4096 + t * 16);
  gload16(Bg + (size_t)128 * 512, Bs_base + 8192 + t * 16);
  gload16(Bg + (size_t)192 * 512, Bs_base + 12288 + t * 16);
  {
    bf16x8 u0 = *(const bf16x8*)(u0p), v0 = *(const bf16x8*)(v0p);
    bf16x8 u1 = *(const bf16x8*)(u1p), v1 = *(const bf16x8*)(v1p);
    float4 bl = *(const float4*)(gp), bh = *(const float4*)(gp + 4);
    bf16x8 o0, o1;
    BUILD_A(o0, u0, v0, bl, bh, ok0);
    BUILD_A(o1, u1, v1, bl, bh, ok1);
    *(bf16x8*)(As_base + rl0 * 32 + wchunk * 8) = o0;
    *(bf16x8*)(As_base + (rl0 + 64) * 32 + wchunk * 8) = o1;
  }
  __syncthreads();

  int cur = 0;
  for (int it = 0; it < 15; ++it) {
    const int nxt = cur ^ 1;
    const int kn = (it + 1) * 32;
    // issue next-tile loads
    gload16(Bg + kn, Bs_base + nxt * 16384 + t * 16);
    gload16(Bg + (size_t)64 * 512 + kn, Bs_base + nxt * 16384 + 4096 + t * 16);
    gload16(Bg + (size_t)128 * 512 + kn, Bs_base + nxt * 16384 + 8192 + t * 16);
    gload16(Bg + (size_t)192 * 512 + kn, Bs_base + nxt * 16384 + 12288 + t * 16);
    bf16x8 u0 = *(const bf16x8*)(u0p + kn), v0 = *(const bf16x8*)(v0p + kn);
    bf16x8 u1 = *(const bf16x8*)(u1p + kn), v1 = *(const bf16x8*)(v1p + kn);
    float4 bl = *(const float4*)(gp + kn), bh = *(const float4*)(gp + kn + 4);
    // compute current
    {
      __bf16* As = As_base + cur * 4096;
      __bf16* Bs = (__bf16*)(Bs_base + cur * 16384);
      bf16x8 fa[4], fb[8];
#pragma unroll
      for (int m = 0; m < 4; m++)
        fa[m] = *(const bf16x8*)(As + (wm + m * 16 + lr) * 32 + rchunk);
#pragma unroll
      for (int n = 0; n < 8; n++)
        fb[n] = *(const bf16x8*)(Bs + (wn + n * 16 + lr) * 32 + rchunk);
#pragma unroll
      for (int m = 0; m < 4; m++)
#pragma unroll
        for (int n = 0; n < 8; n++)
          acc[m][n] = __builtin_amdgcn_mfma_f32_16x16x32_bf16(fa[m], fb[n], acc[m][n], 0, 0, 0);
    }
    // build + write next-tile A
    {
      bf16x8 o0, o1;
      BUILD_A(o0, u0, v0, bl, bh, ok0);
      BUILD_A(o1, u1, v1, bl, bh, ok1);
      *(bf16x8*)(As_base + nxt * 4096 + rl0 * 32 + wchunk * 8) = o0;
      *(bf16x8*)(As_base + nxt * 4096 + (rl0 + 64) * 32 + wchunk * 8) = o1;
    }
    __syncthreads();
    cur = nxt;
  }
  // final compute
  {
    __bf16* As = As_base + cur * 4096;
    __bf16* Bs = (__bf16*)(Bs_base + cur * 16384);
    bf16x8 fa[4], fb[8];
#pragma unroll
    for (int m = 0; m < 4; m++)
      fa[m] = *(const bf16x8*)(As + (wm + m * 16 + lr) * 32 + rchunk);
#pragma unroll
    for (int n = 0; n < 8; n++)
      fb[n] = *(const bf16x8*)(Bs + (wn + n * 16 + lr) * 32 + rchunk);
#pragma unroll
    for (int m = 0; m < 4; m++)
#pragma unroll
      for (int n = 0; n < 8; n++)
        acc[m][n] = __builtin_amdgcn_mfma_f32_16x16x32_bf16(fa[m], fb[n], acc[m][n], 0, 0, 0);
  }

  // epilogue (R3 exact): relu(+bg2) in-register, group reduce via shfl
  if (tm < 32) {
#pragma unroll
    for (int pair = 0; pair < 2; pair++) {
#pragma unroll
      for (int n = 0; n < 8; n++) {
        int col = tnp * 256 + wn + n * 16 + lr;
        float bv = bg2[col];
        float s = 0.0f;
#pragma unroll
        for (int mh = 0; mh < 2; mh++) {
          int m = pair * 2 + mh;
#pragma unroll
          for (int reg = 0; reg < 4; reg++) {
            bool ok = (mh == 0) || (lg * 4 + reg < 14);
            float v = fmaxf(acc[m][n][reg] + bv, 0.0f);
            s += ok ? v : 0.0f;
          }
        }
        s += __shfl_xor(s, 16);
        s += __shfl_xor(s, 32);
        if (l < 16) {
          int g = (wm >> 5) + pair;
          outSS[(size_t)(tm * 4 + g) * 512 + col] = s;
        }
      }
    }
  } else {
#pragma unroll
    for (int m = 0; m < 4; m++) {
#pragma unroll
      for (int n = 0; n < 8; n++) {
        int col = tnp * 256 + wn + n * 16 + lr;
        float bv = bg2[col];
        float s = 0.0f;
#pragma unroll
        for (int reg = 0; reg < 4; reg++) {
          float v = fmaxf(acc[m][n][reg] + bv, 0.0f);
          s += (lg < 3) ? v : 0.0f;
        }
        s += __shfl_xor(s, 16);
        s += __shfl_xor(s, 32);
        if (l < 16) {
          int h = (tm - 32) * 8 + (wm >> 4) + m;
          outSQ[(size_t)h * 512 + col] = s;
        }
      }
    }
  }
#undef BUILD_A
}

// ---------------------------------------------------------------------------
// Layer-3: A rows = bf16(SS[ss]+SQ[gr]) (R3-proven), B = Wf1T. 128x128 tiles,
// 2x2 waves, 2-phase dbuf. Epilogue relu(+bf1) -> H fp32.
__global__ __launch_bounds__(256, 2) void gemm3_fused(
    const float* __restrict__ SS, const float* __restrict__ SQ,
    const __bf16* __restrict__ BT, const float* __restrict__ bias,
    float* __restrict__ H) {
  __shared__ __align__(16) char smem[32768];

  int bid = blockIdx.x;
  { int q = gridDim.x >> 3; bid = (bid & 7) * q + (bid >> 3); }  // 64 % 8 == 0
  const int tm = bid >> 2;   // 0..15
  const int tn = bid & 3;    // 0..3
  const int t = threadIdx.x, w = t >> 6, l = t & 63;
  const int wm = (w >> 1) << 6, wn = (w & 1) << 6;
  const int lr = l & 15, lg = l >> 4;

  const int rl0 = t >> 2, c = t & 3;
  const int wchunk = c ^ ((rl0 >> 2) & 3);
  const int gr0 = tm * 128 + rl0, gr1 = gr0 + 64;
  const int ss0 = (gr0 >> 5) * 2 + (gr0 & 1);
  const int ss1 = (gr1 >> 5) * 2 + (gr1 & 1);
  const float* s0p = SS + (size_t)ss0 * 512 + c * 8;
  const float* q0p = SQ + (size_t)gr0 * 512 + c * 8;
  const float* s1p = SS + (size_t)ss1 * 512 + c * 8;
  const float* q1p = SQ + (size_t)gr1 * 512 + c * 8;

  const int kch = ((t & 3) ^ ((t >> 4) & 3)) * 8;
  const __bf16* Bg = BT + (size_t)(tn * 128 + rl0) * 512 + kch;

  __bf16* As_base = (__bf16*)smem;
  char*   Bs_base = smem + 16384;

  f32x4 acc[4][4];
#pragma unroll
  for (int m = 0; m < 4; m++)
#pragma unroll
    for (int n = 0; n < 4; n++) acc[m][n] = (f32x4){0.f, 0.f, 0.f, 0.f};
  const int rchunk = (lg ^ (lr >> 2)) * 8;

#define BUILD_S(o, a0, a1, b0, b1)                                   \
  {                                                                  \
    o[0] = (__bf16)(a0.x + b0.x); o[1] = (__bf16)(a0.y + b0.y);      \
    o[2] = (__bf16)(a0.z + b0.z); o[3] = (__bf16)(a0.w + b0.w);      \
    o[4] = (__bf16)(a1.x + b1.x); o[5] = (__bf16)(a1.y + b1.y);      \
    o[6] = (__bf16)(a1.z + b1.z); o[7] = (__bf16)(a1.w + b1.w);      \
  }

  // prologue
  gload16(Bg, Bs_base + t * 16);
  gload16(Bg + (size_t)64 * 512, Bs_base + 4096 + t * 16);
  {
    float4 a0 = *(const float4*)(s0p), a1 = *(const float4*)(s0p + 4);
    float4 b0 = *(const float4*)(q0p), b1 = *(const float4*)(q0p + 4);
    float4 c0 = *(const float4*)(s1p), c1 = *(const float4*)(s1p + 4);
    float4 d0 = *(const float4*)(q1p), d1 = *(const float4*)(q1p + 4);
    bf16x8 o0, o1;
    BUILD_S(o0, a0, a1, b0, b1);
    BUILD_S(o1, c0, c1, d0, d1);
    *(bf16x8*)(As_base + rl0 * 32 + wchunk * 8) = o0;
    *(bf16x8*)(As_base + (rl0 + 64) * 32 + wchunk * 8) = o1;
  }
  __syncthreads();

  int cur = 0;
  for (int it = 0; it < 15; ++it) {
    const int nxt = cur ^ 1;
    const int kn = (it + 1) * 32;
    gload16(Bg + kn, Bs_base + nxt * 8192 + t * 16);
    gload16(Bg + (size_t)64 * 512 + kn, Bs_base + nxt * 8192 + 4096 + t * 16);
    float4 a0 = *(const float4*)(s0p + kn), a1 = *(const float4*)(s0p + kn + 4);
    float4 b0 = *(const float4*)(q0p + kn), b1 = *(const float4*)(q0p + kn + 4);
    float4 c0 = *(const float4*)(s1p + kn), c1 = *(const float4*)(s1p + kn + 4);
    float4 d0 = *(const float4*)(q1p + kn), d1 = *(const float4*)(q1p + kn + 4);
    {
      __bf16* As = As_base + cur * 4096;
      __bf16* Bs = (__bf16*)(Bs_base + cur * 8192);
      bf16x8 fa[4], fb[4];
#pragma unroll
      for (int m = 0; m < 4; m++)
        fa[m] = *(const bf16x8*)(As + (wm + m * 16 + lr) * 32 + rchunk);
#pragma unroll
      for (int n = 0; n < 4; n++)
        fb[n] = *(const bf16x8*)(Bs + (wn + n * 16 + lr) * 32 + rchunk);
#pragma unroll
      for (int m = 0; m < 4; m++)
#pragma unroll
        for (int n = 0; n < 4; n++)
          acc[m][n] = __builtin_amdgcn_mfma_f32_16x16x32_bf16(fa[m], fb[n], acc[m][n], 0, 0, 0);
    }
    {
      bf16x8 o0, o1;
      BUILD_S(o0, a0, a1, b0, b1);
      BUILD_S(o1, c0, c1, d0, d1);
      *(bf16x8*)(As_base + nxt * 4096 + rl0 * 32 + wchunk * 8) = o0;
      *(bf16x8*)(As_base + nxt * 4096 + (rl0 + 64) * 32 + wchunk * 8) = o1;
    }
    __syncthreads();
    cur = nxt;
  }
  {
    __bf16* As = As_base + cur * 4096;
    __bf16* Bs = (__bf16*)(Bs_base + cur * 8192);
    bf16x8 fa[4], fb[4];
#pragma unroll
    for (int m = 0; m < 4; m++)
      fa[m] = *(const bf16x8*)(As + (wm + m * 16 + lr) * 32 + rchunk);
#pragma unroll
    for (int n = 0; n < 4; n++)
      fb[n] = *(const bf16x8*)(Bs + (wn + n * 16 + lr) * 32 + rchunk);
#pragma unroll
    for (int m = 0; m < 4; m++)
#pragma unroll
      for (int n = 0; n < 4; n++)
        acc[m][n] = __builtin_amdgcn_mfma_f32_16x16x32_bf16(fa[m], fb[n], acc[m][n], 0, 0, 0);
  }

#pragma unroll
  for (int m = 0; m < 4; m++)
#pragma unroll
    for (int n = 0; n < 4; n++) {
      int col = tn * 128 + wn + n * 16 + lr;
#pragma unroll
      for (int reg = 0; reg < 4; reg++) {
        int row = tm * 128 + wm + m * 16 + lg * 4 + reg;
        H[(size_t)row * 512 + col] = fmaxf(acc[m][n][reg] + bias[col], 0.0f);
      }
    }
#undef BUILD_S
}

// ---------------------------------------------------------------------------
// logits: one wave per row (proven)
__global__ void final_dot(const float* __restrict__ h, const float* __restrict__ Wf2,
                          const float* __restrict__ bf2, float* __restrict__ out) {
  int row = blockIdx.x * 4 + (threadIdx.x >> 6);
  int l = threadIdx.x & 63;
  const float4* hp = (const float4*)(h + (size_t)row * 512);
  const float4* wp = (const float4*)Wf2;
  float s = 0.0f;
#pragma unroll
  for (int i = 0; i < 2; i++) {
    float4 a = hp[l + 64 * i];
    float4 b = wp[l + 64 * i];
    s += a.x * b.x + a.y * b.y + a.z * b.z + a.w * b.w;
  }
#pragma unroll
  for (int off = 32; off; off >>= 1) s += __shfl_down(s, off, 64);
  if (l == 0) out[row] = s + bf2[0];
}

// ---------------------------------------------------------------------------
extern "C" void kernel_launch(void* const* d_in, const int* in_sizes, int n_in,
                              void* d_out, int out_size, void* d_ws, size_t ws_size,
                              hipStream_t stream) {
  const float* xs  = (const float*)d_in[0];
  const float* xq  = (const float*)d_in[1];
  const float* Wg1 = (const float*)d_in[2];
  const float* bg1 = (const float*)d_in[3];
  const float* Wg2 = (const float*)d_in[4];
  const float* bg2 = (const float*)d_in[5];
  const float* Wf1 = (const float*)d_in[6];
  const float* bf1 = (const float*)d_in[7];
  const float* Wf2 = (const float*)d_in[8];
  const float* bf2 = (const float*)d_in[9];
  float* out = (float*)d_out;

  char* ws = (char*)d_ws;
  __bf16* Wg1T = (__bf16*)(ws);             // 1024*512*2 = 1,048,576
  __bf16* Wg2T = (__bf16*)(ws + 1048576);   //   524,288
  __bf16* Wf1T = (__bf16*)(ws + 1572864);   //   524,288
  __bf16* UVb  = (__bf16*)(ws + 2097152);   // 1792*1024*2 = 3,670,016
  float*  SSs  = (float*)(ws + 5767168);    // 128*512*4  = 262,144
  float*  SQs  = (float*)(ws + 6029312);    // 2048*512*4 = 4,194,304
  float*  Hf   = (float*)(ws + 10223616);   // 2048*512*4 = 4,194,304

  convert_w<<<4096, 256, 0, stream>>>(Wg1, Wg2, Wf1, Wg1T, Wg2T, Wf1T);
  gemm1_fused<<<112, 256, 0, stream>>>(xs, xq, Wg1T, UVb);
  gemm2_fused<<<576, 256, 0, stream>>>(UVb, bg1, Wg2T, bg2, SSs, SQs);
  gemm3_fused<<<64, 256, 0, stream>>>(SSs, SQs, Wf1T, bf1, Hf);
  final_dot<<<512, 256, 0, stream>>>(Hf, Wf2, bf2, out);
}

// Round 6
// 82.179 us; speedup vs baseline: 1.3498x; 1.1457x over previous
//
#include <hip/hip_runtime.h>
#include <stdint.h>

typedef __bf16 bf16x8 __attribute__((ext_vector_type(8)));
typedef float f32x4 __attribute__((ext_vector_type(4)));

// ---------------------------------------------------------------------------
__device__ __forceinline__ void gload16(const void* g, void* l) {
  __builtin_amdgcn_global_load_lds((const __attribute__((address_space(1))) void*)g,
                                   (__attribute__((address_space(3))) void*)l,
                                   16, 0, 0);
}

// pair-row mapping for the padded 36864-row layer-2 matrix (proven R3/R5)
__device__ __forceinline__ void maprow(int gr, int& rowU, int& rowV, bool& ok) {
  if (gr < 4096) {
    int g = gr >> 5, p = gr & 31;
    ok = (p < 30);
    int i = p / 5, jj = p % 5;
    int j = jj + (jj >= i);
    rowU = g * 6 + j;
    rowV = g * 6 + i;
  } else {
    int r2 = gr - 4096;
    int h = r2 >> 4, p = r2 & 15;
    ok = (p < 12);
    int b = h >> 5, q = (h >> 1) & 15, wv = h & 1;
    int sbase = (b * 2 + wv) * 6;
    int qrow = 768 + b * 16 + q;
    if (p < 6) { rowU = qrow; rowV = sbase + p; }
    else       { rowU = sbase + (p - 6); rowV = qrow; }
  }
  if (!ok) { rowU = 0; rowV = 0; }
}

__device__ __forceinline__ bf16x8 cvt8(float4 a, float4 b) {
  bf16x8 o;
  o[0] = (__bf16)a.x; o[1] = (__bf16)a.y; o[2] = (__bf16)a.z; o[3] = (__bf16)a.w;
  o[4] = (__bf16)b.x; o[5] = (__bf16)b.y; o[6] = (__bf16)b.z; o[7] = (__bf16)b.w;
  return o;
}

// ---------------------------------------------------------------------------
// weight transposes -> bf16 (proven)
__global__ void convert_w(const float* __restrict__ Wg1, const float* __restrict__ Wg2,
                          const float* __restrict__ Wf1,
                          __bf16* __restrict__ Wg1T, __bf16* __restrict__ Wg2T,
                          __bf16* __restrict__ Wf1T) {
  int e = blockIdx.x * 256 + threadIdx.x;
  if (e < 524288) {
    int c = e >> 9, k = e & 511;
    float v = (c < 512) ? Wg1[k * 512 + c] : Wg1[(512 + k) * 512 + (c - 512)];
    Wg1T[e] = (__bf16)v;
  } else if (e < 786432) {
    int e2 = e - 524288;
    int n = e2 >> 9, k = e2 & 511;
    Wg2T[e2] = (__bf16)Wg2[k * 512 + n];
  } else {
    int e2 = e - 786432;
    int c = e2 >> 9, k = e2 & 511;
    Wf1T[e2] = (__bf16)Wf1[k * 512 + c];
  }
}

// ---------------------------------------------------------------------------
// Layer-1: UVb[1792][1024] = bf16(x) @ Wg1T^T. Tile 128x64, 4 waves (2x2:
// wave tile 64x32, acc[4][2]). A staged from xs/xq (R5 mapping), B 64 rows.
__global__ __launch_bounds__(256, 2) void gemm1_fused(
    const float* __restrict__ xs, const float* __restrict__ xq,
    const __bf16* __restrict__ BT, __bf16* __restrict__ UVb) {
  __shared__ __align__(16) char smem[24576];  // As[2] 16K @0, Bs[2] 8K @16384

  int bid = blockIdx.x;
  { int q = gridDim.x >> 3; bid = (bid & 7) * q + (bid >> 3); }  // 224 % 8 == 0
  const int tm = bid >> 4;   // 0..13
  const int tn = bid & 15;   // 0..15
  const int t = threadIdx.x, w = t >> 6, l = t & 63;
  const int wm = (w >> 1) << 6, wn = (w & 1) << 5;
  const int lr = l & 15, lg = l >> 4;

  const int rl0 = t >> 2, c = t & 3;
  const int wchunk = c ^ ((rl0 >> 2) & 3);
  const int gr0 = tm * 128 + rl0, gr1 = gr0 + 64;
  const float* x0 = ((gr0 < 768) ? xs + (size_t)gr0 * 512 : xq + (size_t)(gr0 - 768) * 512) + c * 8;
  const float* x1 = ((gr1 < 768) ? xs + (size_t)gr1 * 512 : xq + (size_t)(gr1 - 768) * 512) + c * 8;

  const int kch = ((t & 3) ^ ((t >> 4) & 3)) * 8;
  const __bf16* Bg = BT + (size_t)(tn * 64 + rl0) * 512 + kch;  // rl0 in [0,64)

  __bf16* As_base = (__bf16*)smem;     // + cur*4096 elems
  char*   Bs_base = smem + 16384;      // + cur*4096 bytes

  f32x4 acc[4][2];
#pragma unroll
  for (int m = 0; m < 4; m++)
#pragma unroll
    for (int n = 0; n < 2; n++) acc[m][n] = (f32x4){0.f, 0.f, 0.f, 0.f};
  const int rchunk = (lg ^ (lr >> 2)) * 8;

  // prologue
  gload16(Bg, Bs_base + t * 16);
  {
    float4 a0 = *(const float4*)(x0), a1 = *(const float4*)(x0 + 4);
    float4 b0 = *(const float4*)(x1), b1 = *(const float4*)(x1 + 4);
    *(bf16x8*)(As_base + rl0 * 32 + wchunk * 8) = cvt8(a0, a1);
    *(bf16x8*)(As_base + (rl0 + 64) * 32 + wchunk * 8) = cvt8(b0, b1);
  }
  __syncthreads();

  int cur = 0;
  for (int it = 0; it < 15; ++it) {
    const int nxt = cur ^ 1;
    const int kn = (it + 1) * 32;
    gload16(Bg + kn, Bs_base + nxt * 4096 + t * 16);
    float4 a0 = *(const float4*)(x0 + kn), a1 = *(const float4*)(x0 + kn + 4);
    float4 b0 = *(const float4*)(x1 + kn), b1 = *(const float4*)(x1 + kn + 4);
    {
      __bf16* As = As_base + cur * 4096;
      __bf16* Bs = (__bf16*)(Bs_base + cur * 4096);
      bf16x8 fa[4], fb[2];
#pragma unroll
      for (int m = 0; m < 4; m++)
        fa[m] = *(const bf16x8*)(As + (wm + m * 16 + lr) * 32 + rchunk);
#pragma unroll
      for (int n = 0; n < 2; n++)
        fb[n] = *(const bf16x8*)(Bs + (wn + n * 16 + lr) * 32 + rchunk);
#pragma unroll
      for (int m = 0; m < 4; m++)
#pragma unroll
        for (int n = 0; n < 2; n++)
          acc[m][n] = __builtin_amdgcn_mfma_f32_16x16x32_bf16(fa[m], fb[n], acc[m][n], 0, 0, 0);
    }
    *(bf16x8*)(As_base + nxt * 4096 + rl0 * 32 + wchunk * 8) = cvt8(a0, a1);
    *(bf16x8*)(As_base + nxt * 4096 + (rl0 + 64) * 32 + wchunk * 8) = cvt8(b0, b1);
    __syncthreads();
    cur = nxt;
  }
  {
    __bf16* As = As_base + cur * 4096;
    __bf16* Bs = (__bf16*)(Bs_base + cur * 4096);
    bf16x8 fa[4], fb[2];
#pragma unroll
    for (int m = 0; m < 4; m++)
      fa[m] = *(const bf16x8*)(As + (wm + m * 16 + lr) * 32 + rchunk);
#pragma unroll
    for (int n = 0; n < 2; n++)
      fb[n] = *(const bf16x8*)(Bs + (wn + n * 16 + lr) * 32 + rchunk);
#pragma unroll
    for (int m = 0; m < 4; m++)
#pragma unroll
      for (int n = 0; n < 2; n++)
        acc[m][n] = __builtin_amdgcn_mfma_f32_16x16x32_bf16(fa[m], fb[n], acc[m][n], 0, 0, 0);
  }

#pragma unroll
  for (int m = 0; m < 4; m++)
#pragma unroll
    for (int n = 0; n < 2; n++) {
      int col = tn * 64 + wn + n * 16 + lr;
#pragma unroll
      for (int reg = 0; reg < 4; reg++) {
        int row = tm * 128 + wm + m * 16 + lg * 4 + reg;
        UVb[(size_t)row * 1024 + col] = (__bf16)acc[m][n][reg];
      }
    }
}

// ---------------------------------------------------------------------------
// Layer-2: A rows = relu(U+V+bg1) from bf16 UVb (R5-proven staging/mapping),
// B = Wg2T. Tile 128x128 (2x2 waves, acc[4][4]), 2-phase dbuf, 32K LDS.
// Epilogue: relu(+bg2) + group row-reduce (R5 exact formulas).
__global__ __launch_bounds__(256, 2) void gemm2_fused(
    const __bf16* __restrict__ UVb, const float* __restrict__ bg1,
    const __bf16* __restrict__ BT, const float* __restrict__ bg2,
    float* __restrict__ outSS, float* __restrict__ outSQ) {
  __shared__ __align__(16) char smem[32768];  // As[2] 16K @0, Bs[2] 16K @16384

  int bid = blockIdx.x;
  { int q = gridDim.x >> 3; bid = (bid & 7) * q + (bid >> 3); }  // 1152 % 8 == 0
  const int tm = bid >> 2;   // 0..287 (tm<32 -> SS region)
  const int tn = bid & 3;    // 0..3
  const int t = threadIdx.x, w = t >> 6, l = t & 63;
  const int wm = (w >> 1) << 6;   // 0/64
  const int wn = (w & 1) << 6;    // 0/64
  const int lr = l & 15, lg = l >> 4;

  const int rl0 = t >> 2, c = t & 3;
  const int wchunk = c ^ ((rl0 >> 2) & 3);
  int rU0, rV0, rU1, rV1; bool ok0, ok1;
  maprow(tm * 128 + rl0, rU0, rV0, ok0);
  maprow(tm * 128 + rl0 + 64, rU1, rV1, ok1);
  const __bf16* u0p = UVb + (size_t)rU0 * 1024 + c * 8;
  const __bf16* v0p = UVb + (size_t)rV0 * 1024 + 512 + c * 8;
  const __bf16* u1p = UVb + (size_t)rU1 * 1024 + c * 8;
  const __bf16* v1p = UVb + (size_t)rV1 * 1024 + 512 + c * 8;
  const float* gp = bg1 + c * 8;

  const int kch = ((t & 3) ^ ((t >> 4) & 3)) * 8;
  const __bf16* Bg = BT + (size_t)(tn * 128 + rl0) * 512 + kch;

  __bf16* As_base = (__bf16*)smem;     // + cur*4096 elems
  char*   Bs_base = smem + 16384;      // + cur*8192 bytes

  f32x4 acc[4][4];
#pragma unroll
  for (int m = 0; m < 4; m++)
#pragma unroll
    for (int n = 0; n < 4; n++) acc[m][n] = (f32x4){0.f, 0.f, 0.f, 0.f};
  const int rchunk = (lg ^ (lr >> 2)) * 8;

#define BUILD_A(o, u, v, bl, bh, okk)                                      \
  {                                                                        \
    if (okk) {                                                             \
      o[0] = (__bf16)fmaxf((float)u[0] + (float)v[0] + bl.x, 0.f);         \
      o[1] = (__bf16)fmaxf((float)u[1] + (float)v[1] + bl.y, 0.f);         \
      o[2] = (__bf16)fmaxf((float)u[2] + (float)v[2] + bl.z, 0.f);         \
      o[3] = (__bf16)fmaxf((float)u[3] + (float)v[3] + bl.w, 0.f);         \
      o[4] = (__bf16)fmaxf((float)u[4] + (float)v[4] + bh.x, 0.f);         \
      o[5] = (__bf16)fmaxf((float)u[5] + (float)v[5] + bh.y, 0.f);         \
      o[6] = (__bf16)fmaxf((float)u[6] + (float)v[6] + bh.z, 0.f);         \
      o[7] = (__bf16)fmaxf((float)u[7] + (float)v[7] + bh.w, 0.f);         \
    } else {                                                               \
      for (int e = 0; e < 8; e++) o[e] = (__bf16)0.0f;                     \
    }                                                                      \
  }

  // prologue
  gload16(Bg, Bs_base + t * 16);
  gload16(Bg + (size_t)64 * 512, Bs_base + 4096 + t * 16);
  {
    bf16x8 u0 = *(const bf16x8*)(u0p), v0 = *(const bf16x8*)(v0p);
    bf16x8 u1 = *(const bf16x8*)(u1p), v1 = *(const bf16x8*)(v1p);
    float4 bl = *(const float4*)(gp), bh = *(const float4*)(gp + 4);
    bf16x8 o0, o1;
    BUILD_A(o0, u0, v0, bl, bh, ok0);
    BUILD_A(o1, u1, v1, bl, bh, ok1);
    *(bf16x8*)(As_base + rl0 * 32 + wchunk * 8) = o0;
    *(bf16x8*)(As_base + (rl0 + 64) * 32 + wchunk * 8) = o1;
  }
  __syncthreads();

  int cur = 0;
  for (int it = 0; it < 15; ++it) {
    const int nxt = cur ^ 1;
    const int kn = (it + 1) * 32;
    gload16(Bg + kn, Bs_base + nxt * 8192 + t * 16);
    gload16(Bg + (size_t)64 * 512 + kn, Bs_base + nxt * 8192 + 4096 + t * 16);
    bf16x8 u0 = *(const bf16x8*)(u0p + kn), v0 = *(const bf16x8*)(v0p + kn);
    bf16x8 u1 = *(const bf16x8*)(u1p + kn), v1 = *(const bf16x8*)(v1p + kn);
    float4 bl = *(const float4*)(gp + kn), bh = *(const float4*)(gp + kn + 4);
    {
      __bf16* As = As_base + cur * 4096;
      __bf16* Bs = (__bf16*)(Bs_base + cur * 8192);
      bf16x8 fa[4], fb[4];
#pragma unroll
      for (int m = 0; m < 4; m++)
        fa[m] = *(const bf16x8*)(As + (wm + m * 16 + lr) * 32 + rchunk);
#pragma unroll
      for (int n = 0; n < 4; n++)
        fb[n] = *(const bf16x8*)(Bs + (wn + n * 16 + lr) * 32 + rchunk);
#pragma unroll
      for (int m = 0; m < 4; m++)
#pragma unroll
        for (int n = 0; n < 4; n++)
          acc[m][n] = __builtin_amdgcn_mfma_f32_16x16x32_bf16(fa[m], fb[n], acc[m][n], 0, 0, 0);
    }
    {
      bf16x8 o0, o1;
      BUILD_A(o0, u0, v0, bl, bh, ok0);
      BUILD_A(o1, u1, v1, bl, bh, ok1);
      *(bf16x8*)(As_base + nxt * 4096 + rl0 * 32 + wchunk * 8) = o0;
      *(bf16x8*)(As_base + nxt * 4096 + (rl0 + 64) * 32 + wchunk * 8) = o1;
    }
    __syncthreads();
    cur = nxt;
  }
  {
    __bf16* As = As_base + cur * 4096;
    __bf16* Bs = (__bf16*)(Bs_base + cur * 8192);
    bf16x8 fa[4], fb[4];
#pragma unroll
    for (int m = 0; m < 4; m++)
      fa[m] = *(const bf16x8*)(As + (wm + m * 16 + lr) * 32 + rchunk);
#pragma unroll
    for (int n = 0; n < 4; n++)
      fb[n] = *(const bf16x8*)(Bs + (wn + n * 16 + lr) * 32 + rchunk);
#pragma unroll
    for (int m = 0; m < 4; m++)
#pragma unroll
      for (int n = 0; n < 4; n++)
        acc[m][n] = __builtin_amdgcn_mfma_f32_16x16x32_bf16(fa[m], fb[n], acc[m][n], 0, 0, 0);
  }

  // epilogue (R5 exact, cols now tn*128 base, n<4)
  if (tm < 32) {
#pragma unroll
    for (int pair = 0; pair < 2; pair++) {
#pragma unroll
      for (int n = 0; n < 4; n++) {
        int col = tn * 128 + wn + n * 16 + lr;
        float bv = bg2[col];
        float s = 0.0f;
#pragma unroll
        for (int mh = 0; mh < 2; mh++) {
          int m = pair * 2 + mh;
#pragma unroll
          for (int reg = 0; reg < 4; reg++) {
            bool ok = (mh == 0) || (lg * 4 + reg < 14);
            float v = fmaxf(acc[m][n][reg] + bv, 0.0f);
            s += ok ? v : 0.0f;
          }
        }
        s += __shfl_xor(s, 16);
        s += __shfl_xor(s, 32);
        if (l < 16) {
          int g = (wm >> 5) + pair;
          outSS[(size_t)(tm * 4 + g) * 512 + col] = s;
        }
      }
    }
  } else {
#pragma unroll
    for (int m = 0; m < 4; m++) {
#pragma unroll
      for (int n = 0; n < 4; n++) {
        int col = tn * 128 + wn + n * 16 + lr;
        float bv = bg2[col];
        float s = 0.0f;
#pragma unroll
        for (int reg = 0; reg < 4; reg++) {
          float v = fmaxf(acc[m][n][reg] + bv, 0.0f);
          s += (lg < 3) ? v : 0.0f;
        }
        s += __shfl_xor(s, 16);
        s += __shfl_xor(s, 32);
        if (l < 16) {
          int h = (tm - 32) * 8 + (wm >> 4) + m;
          outSQ[(size_t)h * 512 + col] = s;
        }
      }
    }
  }
#undef BUILD_A
}

// ---------------------------------------------------------------------------
// Layer-3: A rows = bf16(SS[ss]+SQ[gr]) (R5-proven), B = Wf1T. Tile 128x64
// (2x2 waves, acc[4][2]). Epilogue relu(+bf1) -> H fp32.
__global__ __launch_bounds__(256, 2) void gemm3_fused(
    const float* __restrict__ SS, const float* __restrict__ SQ,
    const __bf16* __restrict__ BT, const float* __restrict__ bias,
    float* __restrict__ H) {
  __shared__ __align__(16) char smem[24576];  // As[2] 16K, Bs[2] 8K

  int bid = blockIdx.x;
  { int q = gridDim.x >> 3; bid = (bid & 7) * q + (bid >> 3); }  // 128 % 8 == 0
  const int tm = bid >> 3;   // 0..15
  const int tn = bid & 7;    // 0..7
  const int t = threadIdx.x, w = t >> 6, l = t & 63;
  const int wm = (w >> 1) << 6, wn = (w & 1) << 5;
  const int lr = l & 15, lg = l >> 4;

  const int rl0 = t >> 2, c = t & 3;
  const int wchunk = c ^ ((rl0 >> 2) & 3);
  const int gr0 = tm * 128 + rl0, gr1 = gr0 + 64;
  const int ss0 = (gr0 >> 5) * 2 + (gr0 & 1);
  const int ss1 = (gr1 >> 5) * 2 + (gr1 & 1);
  const float* s0p = SS + (size_t)ss0 * 512 + c * 8;
  const float* q0p = SQ + (size_t)gr0 * 512 + c * 8;
  const float* s1p = SS + (size_t)ss1 * 512 + c * 8;
  const float* q1p = SQ + (size_t)gr1 * 512 + c * 8;

  const int kch = ((t & 3) ^ ((t >> 4) & 3)) * 8;
  const __bf16* Bg = BT + (size_t)(tn * 64 + rl0) * 512 + kch;

  __bf16* As_base = (__bf16*)smem;
  char*   Bs_base = smem + 16384;

  f32x4 acc[4][2];
#pragma unroll
  for (int m = 0; m < 4; m++)
#pragma unroll
    for (int n = 0; n < 2; n++) acc[m][n] = (f32x4){0.f, 0.f, 0.f, 0.f};
  const int rchunk = (lg ^ (lr >> 2)) * 8;

#define BUILD_S(o, a0, a1, b0, b1)                                   \
  {                                                                  \
    o[0] = (__bf16)(a0.x + b0.x); o[1] = (__bf16)(a0.y + b0.y);      \
    o[2] = (__bf16)(a0.z + b0.z); o[3] = (__bf16)(a0.w + b0.w);      \
    o[4] = (__bf16)(a1.x + b1.x); o[5] = (__bf16)(a1.y + b1.y);      \
    o[6] = (__bf16)(a1.z + b1.z); o[7] = (__bf16)(a1.w + b1.w);      \
  }

  // prologue
  gload16(Bg, Bs_base + t * 16);
  {
    float4 a0 = *(const float4*)(s0p), a1 = *(const float4*)(s0p + 4);
    float4 b0 = *(const float4*)(q0p), b1 = *(const float4*)(q0p + 4);
    float4 c0 = *(const float4*)(s1p), c1 = *(const float4*)(s1p + 4);
    float4 d0 = *(const float4*)(q1p), d1 = *(const float4*)(q1p + 4);
    bf16x8 o0, o1;
    BUILD_S(o0, a0, a1, b0, b1);
    BUILD_S(o1, c0, c1, d0, d1);
    *(bf16x8*)(As_base + rl0 * 32 + wchunk * 8) = o0;
    *(bf16x8*)(As_base + (rl0 + 64) * 32 + wchunk * 8) = o1;
  }
  __syncthreads();

  int cur = 0;
  for (int it = 0; it < 15; ++it) {
    const int nxt = cur ^ 1;
    const int kn = (it + 1) * 32;
    gload16(Bg + kn, Bs_base + nxt * 4096 + t * 16);
    float4 a0 = *(const float4*)(s0p + kn), a1 = *(const float4*)(s0p + kn + 4);
    float4 b0 = *(const float4*)(q0p + kn), b1 = *(const float4*)(q0p + kn + 4);
    float4 c0 = *(const float4*)(s1p + kn), c1 = *(const float4*)(s1p + kn + 4);
    float4 d0 = *(const float4*)(q1p + kn), d1 = *(const float4*)(q1p + kn + 4);
    {
      __bf16* As = As_base + cur * 4096;
      __bf16* Bs = (__bf16*)(Bs_base + cur * 4096);
      bf16x8 fa[4], fb[2];
#pragma unroll
      for (int m = 0; m < 4; m++)
        fa[m] = *(const bf16x8*)(As + (wm + m * 16 + lr) * 32 + rchunk);
#pragma unroll
      for (int n = 0; n < 2; n++)
        fb[n] = *(const bf16x8*)(Bs + (wn + n * 16 + lr) * 32 + rchunk);
#pragma unroll
      for (int m = 0; m < 4; m++)
#pragma unroll
        for (int n = 0; n < 2; n++)
          acc[m][n] = __builtin_amdgcn_mfma_f32_16x16x32_bf16(fa[m], fb[n], acc[m][n], 0, 0, 0);
    }
    {
      bf16x8 o0, o1;
      BUILD_S(o0, a0, a1, b0, b1);
      BUILD_S(o1, c0, c1, d0, d1);
      *(bf16x8*)(As_base + nxt * 4096 + rl0 * 32 + wchunk * 8) = o0;
      *(bf16x8*)(As_base + nxt * 4096 + (rl0 + 64) * 32 + wchunk * 8) = o1;
    }
    __syncthreads();
    cur = nxt;
  }
  {
    __bf16* As = As_base + cur * 4096;
    __bf16* Bs = (__bf16*)(Bs_base + cur * 4096);
    bf16x8 fa[4], fb[2];
#pragma unroll
    for (int m = 0; m < 4; m++)
      fa[m] = *(const bf16x8*)(As + (wm + m * 16 + lr) * 32 + rchunk);
#pragma unroll
    for (int n = 0; n < 2; n++)
      fb[n] = *(const bf16x8*)(Bs + (wn + n * 16 + lr) * 32 + rchunk);
#pragma unroll
    for (int m = 0; m < 4; m++)
#pragma unroll
      for (int n = 0; n < 2; n++)
        acc[m][n] = __builtin_amdgcn_mfma_f32_16x16x32_bf16(fa[m], fb[n], acc[m][n], 0, 0, 0);
  }

#pragma unroll
  for (int m = 0; m < 4; m++)
#pragma unroll
    for (int n = 0; n < 2; n++) {
      int col = tn * 64 + wn + n * 16 + lr;
#pragma unroll
      for (int reg = 0; reg < 4; reg++) {
        int row = tm * 128 + wm + m * 16 + lg * 4 + reg;
        H[(size_t)row * 512 + col] = fmaxf(acc[m][n][reg] + bias[col], 0.0f);
      }
    }
#undef BUILD_S
}

// ---------------------------------------------------------------------------
// logits: one wave per row (proven)
__global__ void final_dot(const float* __restrict__ h, const float* __restrict__ Wf2,
                          const float* __restrict__ bf2, float* __restrict__ out) {
  int row = blockIdx.x * 4 + (threadIdx.x >> 6);
  int l = threadIdx.x & 63;
  const float4* hp = (const float4*)(h + (size_t)row * 512);
  const float4* wp = (const float4*)Wf2;
  float s = 0.0f;
#pragma unroll
  for (int i = 0; i < 2; i++) {
    float4 a = hp[l + 64 * i];
    float4 b = wp[l + 64 * i];
    s += a.x * b.x + a.y * b.y + a.z * b.z + a.w * b.w;
  }
#pragma unroll
  for (int off = 32; off; off >>= 1) s += __shfl_down(s, off, 64);
  if (l == 0) out[row] = s + bf2[0];
}

// ---------------------------------------------------------------------------
extern "C" void kernel_launch(void* const* d_in, const int* in_sizes, int n_in,
                              void* d_out, int out_size, void* d_ws, size_t ws_size,
                              hipStream_t stream) {
  const float* xs  = (const float*)d_in[0];
  const float* xq  = (const float*)d_in[1];
  const float* Wg1 = (const float*)d_in[2];
  const float* bg1 = (const float*)d_in[3];
  const float* Wg2 = (const float*)d_in[4];
  const float* bg2 = (const float*)d_in[5];
  const float* Wf1 = (const float*)d_in[6];
  const float* bf1 = (const float*)d_in[7];
  const float* Wf2 = (const float*)d_in[8];
  const float* bf2 = (const float*)d_in[9];
  float* out = (float*)d_out;

  char* ws = (char*)d_ws;
  __bf16* Wg1T = (__bf16*)(ws);             // 1,048,576
  __bf16* Wg2T = (__bf16*)(ws + 1048576);   //   524,288
  __bf16* Wf1T = (__bf16*)(ws + 1572864);   //   524,288
  __bf16* UVb  = (__bf16*)(ws + 2097152);   // 3,670,016
  float*  SSs  = (float*)(ws + 5767168);    //   262,144
  float*  SQs  = (float*)(ws + 6029312);    // 4,194,304
  float*  Hf   = (float*)(ws + 10223616);   // 4,194,304

  convert_w<<<4096, 256, 0, stream>>>(Wg1, Wg2, Wf1, Wg1T, Wg2T, Wf1T);
  gemm1_fused<<<224, 256, 0, stream>>>(xs, xq, Wg1T, UVb);
  gemm2_fused<<<1152, 256, 0, stream>>>(UVb, bg1, Wg2T, bg2, SSs, SQs);
  gemm3_fused<<<128, 256, 0, stream>>>(SSs, SQs, Wf1T, bf1, Hf);
  final_dot<<<512, 256, 0, stream>>>(Hf, Wf2, bf2, out);
}

// Round 7
// 76.888 us; speedup vs baseline: 1.4427x; 1.0688x over previous
//
#include <hip/hip_runtime.h>
#include <stdint.h>

typedef _Float16 f16x8 __attribute__((ext_vector_type(8)));
typedef float f32x4 __attribute__((ext_vector_type(4)));

// ---------------------------------------------------------------------------
__device__ __forceinline__ void gload16(const void* g, void* l) {
  __builtin_amdgcn_global_load_lds((const __attribute__((address_space(1))) void*)g,
                                   (__attribute__((address_space(3))) void*)l,
                                   16, 0, 0);
}

// pair-row mapping for the padded 36864-row layer-2 matrix (proven R3/R5/R6)
__device__ __forceinline__ void maprow(int gr, int& rowU, int& rowV, bool& ok) {
  if (gr < 4096) {
    int g = gr >> 5, p = gr & 31;
    ok = (p < 30);
    int i = p / 5, jj = p % 5;
    int j = jj + (jj >= i);
    rowU = g * 6 + j;
    rowV = g * 6 + i;
  } else {
    int r2 = gr - 4096;
    int h = r2 >> 4, p = r2 & 15;
    ok = (p < 12);
    int b = h >> 5, q = (h >> 1) & 15, wv = h & 1;
    int sbase = (b * 2 + wv) * 6;
    int qrow = 768 + b * 16 + q;
    if (p < 6) { rowU = qrow; rowV = sbase + p; }
    else       { rowU = sbase + (p - 6); rowV = qrow; }
  }
  if (!ok) { rowU = 0; rowV = 0; }
}

__device__ __forceinline__ f16x8 cvt8h(float4 a, float4 b) {
  f16x8 o;
  o[0] = (_Float16)a.x; o[1] = (_Float16)a.y; o[2] = (_Float16)a.z; o[3] = (_Float16)a.w;
  o[4] = (_Float16)b.x; o[5] = (_Float16)b.y; o[6] = (_Float16)b.z; o[7] = (_Float16)b.w;
  return o;
}

// ---------------------------------------------------------------------------
// Weight transposes -> f16, wave-coalesced reads (lanes sweep dest cols).
//  dest layout (flat threads tt, 8 k-elems each):
//   R0 tt in [0,65536):  Wg1T[c][k0..7], c=tt%1024, k0=(tt/1024)*8
//   R1 tt2 in [0,32768): Wg2T[c][k0..7], c=tt2%512, k0=(tt2/512)*8
//   R2 tt3 in [0,32768): Wf1T[c][k0..7]
__global__ void convert_t(const float* __restrict__ Wg1, const float* __restrict__ Wg2,
                          const float* __restrict__ Wf1,
                          _Float16* __restrict__ Wg1T, _Float16* __restrict__ Wg2T,
                          _Float16* __restrict__ Wf1T) {
  int tt = blockIdx.x * 256 + threadIdx.x;  // 512 blocks
  const float* src;
  _Float16* dst;
  int c, k0, scol, srow0;
  if (tt < 65536) {
    c = tt & 1023; k0 = (tt >> 10) << 3;
    dst = Wg1T + (size_t)c * 512 + k0;
    if (c < 512) { src = Wg1; scol = c; srow0 = k0; }
    else         { src = Wg1; scol = c - 512; srow0 = 512 + k0; }
  } else if (tt < 98304) {
    int t2 = tt - 65536;
    c = t2 & 511; k0 = (t2 >> 9) << 3;
    dst = Wg2T + (size_t)c * 512 + k0;
    src = Wg2; scol = c; srow0 = k0;
  } else {
    int t3 = tt - 98304;
    c = t3 & 511; k0 = (t3 >> 9) << 3;
    dst = Wf1T + (size_t)c * 512 + k0;
    src = Wf1; scol = c; srow0 = k0;
  }
  f16x8 o;
#pragma unroll
  for (int i = 0; i < 8; i++)
    o[i] = (_Float16)src[(size_t)(srow0 + i) * 512 + scol];
  *(f16x8*)dst = o;
}

// ---------------------------------------------------------------------------
// Layer-1: UVh[1792][1024] = f16(x) @ Wg1T^T, bg1 folded into V-half cols.
// Tile 128x64, 2x2 waves (R6 geometry), 2-phase dbuf.
__global__ __launch_bounds__(256, 2) void gemm1_fused(
    const float* __restrict__ xs, const float* __restrict__ xq,
    const _Float16* __restrict__ BT, const float* __restrict__ bg1,
    _Float16* __restrict__ UVh) {
  __shared__ __align__(16) char smem[24576];  // As[2] 16K @0, Bs[2] 8K @16384

  int bid = blockIdx.x;
  { int q = gridDim.x >> 3; bid = (bid & 7) * q + (bid >> 3); }  // 224 % 8 == 0
  const int tm = bid >> 4;   // 0..13
  const int tn = bid & 15;   // 0..15
  const int t = threadIdx.x, w = t >> 6, l = t & 63;
  const int wm = (w >> 1) << 6, wn = (w & 1) << 5;
  const int lr = l & 15, lg = l >> 4;

  const int rl0 = t >> 2, c = t & 3;
  const int wchunk = c ^ ((rl0 >> 2) & 3);
  const int gr0 = tm * 128 + rl0, gr1 = gr0 + 64;
  const float* x0 = ((gr0 < 768) ? xs + (size_t)gr0 * 512 : xq + (size_t)(gr0 - 768) * 512) + c * 8;
  const float* x1 = ((gr1 < 768) ? xs + (size_t)gr1 * 512 : xq + (size_t)(gr1 - 768) * 512) + c * 8;

  const int kch = ((t & 3) ^ ((t >> 4) & 3)) * 8;
  const _Float16* Bg = BT + (size_t)(tn * 64 + rl0) * 512 + kch;

  _Float16* As_base = (_Float16*)smem;  // + cur*4096 elems
  char*     Bs_base = smem + 16384;     // + cur*4096 bytes

  f32x4 acc[4][2];
#pragma unroll
  for (int m = 0; m < 4; m++)
#pragma unroll
    for (int n = 0; n < 2; n++) acc[m][n] = (f32x4){0.f, 0.f, 0.f, 0.f};
  const int rchunk = (lg ^ (lr >> 2)) * 8;

  // prologue
  gload16(Bg, Bs_base + t * 16);
  {
    float4 a0 = *(const float4*)(x0), a1 = *(const float4*)(x0 + 4);
    float4 b0 = *(const float4*)(x1), b1 = *(const float4*)(x1 + 4);
    *(f16x8*)(As_base + rl0 * 32 + wchunk * 8) = cvt8h(a0, a1);
    *(f16x8*)(As_base + (rl0 + 64) * 32 + wchunk * 8) = cvt8h(b0, b1);
  }
  __syncthreads();

  int cur = 0;
  for (int it = 0; it < 15; ++it) {
    const int nxt = cur ^ 1;
    const int kn = (it + 1) * 32;
    gload16(Bg + kn, Bs_base + nxt * 4096 + t * 16);
    float4 a0 = *(const float4*)(x0 + kn), a1 = *(const float4*)(x0 + kn + 4);
    float4 b0 = *(const float4*)(x1 + kn), b1 = *(const float4*)(x1 + kn + 4);
    {
      _Float16* As = As_base + cur * 4096;
      _Float16* Bs = (_Float16*)(Bs_base + cur * 4096);
      f16x8 fa[4], fb[2];
#pragma unroll
      for (int m = 0; m < 4; m++)
        fa[m] = *(const f16x8*)(As + (wm + m * 16 + lr) * 32 + rchunk);
#pragma unroll
      for (int n = 0; n < 2; n++)
        fb[n] = *(const f16x8*)(Bs + (wn + n * 16 + lr) * 32 + rchunk);
#pragma unroll
      for (int m = 0; m < 4; m++)
#pragma unroll
        for (int n = 0; n < 2; n++)
          acc[m][n] = __builtin_amdgcn_mfma_f32_16x16x32_f16(fa[m], fb[n], acc[m][n], 0, 0, 0);
    }
    *(f16x8*)(As_base + nxt * 4096 + rl0 * 32 + wchunk * 8) = cvt8h(a0, a1);
    *(f16x8*)(As_base + nxt * 4096 + (rl0 + 64) * 32 + wchunk * 8) = cvt8h(b0, b1);
    __syncthreads();
    cur = nxt;
  }
  {
    _Float16* As = As_base + cur * 4096;
    _Float16* Bs = (_Float16*)(Bs_base + cur * 4096);
    f16x8 fa[4], fb[2];
#pragma unroll
    for (int m = 0; m < 4; m++)
      fa[m] = *(const f16x8*)(As + (wm + m * 16 + lr) * 32 + rchunk);
#pragma unroll
    for (int n = 0; n < 2; n++)
      fb[n] = *(const f16x8*)(Bs + (wn + n * 16 + lr) * 32 + rchunk);
#pragma unroll
    for (int m = 0; m < 4; m++)
#pragma unroll
      for (int n = 0; n < 2; n++)
        acc[m][n] = __builtin_amdgcn_mfma_f32_16x16x32_f16(fa[m], fb[n], acc[m][n], 0, 0, 0);
  }

#pragma unroll
  for (int m = 0; m < 4; m++)
#pragma unroll
    for (int n = 0; n < 2; n++) {
      int col = tn * 64 + wn + n * 16 + lr;
      float bv = (col >= 512) ? bg1[col - 512] : 0.0f;  // fold bg1 into V-half
#pragma unroll
      for (int reg = 0; reg < 4; reg++) {
        int row = tm * 128 + wm + m * 16 + lg * 4 + reg;
        UVh[(size_t)row * 1024 + col] = (_Float16)(acc[m][n][reg] + bv);
      }
    }
}

// ---------------------------------------------------------------------------
// Layer-2: A rows = relu(U+V) via packed f16 (bias pre-folded), B = Wg2T.
// Tile 128x128 (R6 geometry exactly), 2-phase dbuf, 32K LDS.
__global__ __launch_bounds__(256, 2) void gemm2_fused(
    const _Float16* __restrict__ UVh,
    const _Float16* __restrict__ BT, const float* __restrict__ bg2,
    float* __restrict__ outSS, float* __restrict__ outSQ) {
  __shared__ __align__(16) char smem[32768];  // As[2] 16K @0, Bs[2] 16K @16384

  int bid = blockIdx.x;
  { int q = gridDim.x >> 3; bid = (bid & 7) * q + (bid >> 3); }  // 1152 % 8 == 0
  const int tm = bid >> 2;   // 0..287 (tm<32 -> SS region)
  const int tn = bid & 3;    // 0..3
  const int t = threadIdx.x, w = t >> 6, l = t & 63;
  const int wm = (w >> 1) << 6;
  const int wn = (w & 1) << 6;
  const int lr = l & 15, lg = l >> 4;

  const int rl0 = t >> 2, c = t & 3;
  const int wchunk = c ^ ((rl0 >> 2) & 3);
  int rU0, rV0, rU1, rV1; bool ok0, ok1;
  maprow(tm * 128 + rl0, rU0, rV0, ok0);
  maprow(tm * 128 + rl0 + 64, rU1, rV1, ok1);
  const _Float16* u0p = UVh + (size_t)rU0 * 1024 + c * 8;
  const _Float16* v0p = UVh + (size_t)rV0 * 1024 + 512 + c * 8;
  const _Float16* u1p = UVh + (size_t)rU1 * 1024 + c * 8;
  const _Float16* v1p = UVh + (size_t)rV1 * 1024 + 512 + c * 8;

  const int kch = ((t & 3) ^ ((t >> 4) & 3)) * 8;
  const _Float16* Bg = BT + (size_t)(tn * 128 + rl0) * 512 + kch;

  _Float16* As_base = (_Float16*)smem;  // + cur*4096 elems
  char*     Bs_base = smem + 16384;     // + cur*8192 bytes

  f32x4 acc[4][4];
#pragma unroll
  for (int m = 0; m < 4; m++)
#pragma unroll
    for (int n = 0; n < 4; n++) acc[m][n] = (f32x4){0.f, 0.f, 0.f, 0.f};
  const int rchunk = (lg ^ (lr >> 2)) * 8;

  const f16x8 zz = {};

  // prologue
  gload16(Bg, Bs_base + t * 16);
  gload16(Bg + (size_t)64 * 512, Bs_base + 4096 + t * 16);
  {
    f16x8 u0 = *(const f16x8*)(u0p), v0 = *(const f16x8*)(v0p);
    f16x8 u1 = *(const f16x8*)(u1p), v1 = *(const f16x8*)(v1p);
    f16x8 o0 = ok0 ? __builtin_elementwise_max(u0 + v0, zz) : zz;
    f16x8 o1 = ok1 ? __builtin_elementwise_max(u1 + v1, zz) : zz;
    *(f16x8*)(As_base + rl0 * 32 + wchunk * 8) = o0;
    *(f16x8*)(As_base + (rl0 + 64) * 32 + wchunk * 8) = o1;
  }
  __syncthreads();

  int cur = 0;
  for (int it = 0; it < 15; ++it) {
    const int nxt = cur ^ 1;
    const int kn = (it + 1) * 32;
    gload16(Bg + kn, Bs_base + nxt * 8192 + t * 16);
    gload16(Bg + (size_t)64 * 512 + kn, Bs_base + nxt * 8192 + 4096 + t * 16);
    f16x8 u0 = *(const f16x8*)(u0p + kn), v0 = *(const f16x8*)(v0p + kn);
    f16x8 u1 = *(const f16x8*)(u1p + kn), v1 = *(const f16x8*)(v1p + kn);
    {
      _Float16* As = As_base + cur * 4096;
      _Float16* Bs = (_Float16*)(Bs_base + cur * 8192);
      f16x8 fa[4], fb[4];
#pragma unroll
      for (int m = 0; m < 4; m++)
        fa[m] = *(const f16x8*)(As + (wm + m * 16 + lr) * 32 + rchunk);
#pragma unroll
      for (int n = 0; n < 4; n++)
        fb[n] = *(const f16x8*)(Bs + (wn + n * 16 + lr) * 32 + rchunk);
#pragma unroll
      for (int m = 0; m < 4; m++)
#pragma unroll
        for (int n = 0; n < 4; n++)
          acc[m][n] = __builtin_amdgcn_mfma_f32_16x16x32_f16(fa[m], fb[n], acc[m][n], 0, 0, 0);
    }
    {
      f16x8 o0 = ok0 ? __builtin_elementwise_max(u0 + v0, zz) : zz;
      f16x8 o1 = ok1 ? __builtin_elementwise_max(u1 + v1, zz) : zz;
      *(f16x8*)(As_base + nxt * 4096 + rl0 * 32 + wchunk * 8) = o0;
      *(f16x8*)(As_base + nxt * 4096 + (rl0 + 64) * 32 + wchunk * 8) = o1;
    }
    __syncthreads();
    cur = nxt;
  }
  {
    _Float16* As = As_base + cur * 4096;
    _Float16* Bs = (_Float16*)(Bs_base + cur * 8192);
    f16x8 fa[4], fb[4];
#pragma unroll
    for (int m = 0; m < 4; m++)
      fa[m] = *(const f16x8*)(As + (wm + m * 16 + lr) * 32 + rchunk);
#pragma unroll
    for (int n = 0; n < 4; n++)
      fb[n] = *(const f16x8*)(Bs + (wn + n * 16 + lr) * 32 + rchunk);
#pragma unroll
    for (int m = 0; m < 4; m++)
#pragma unroll
      for (int n = 0; n < 4; n++)
        acc[m][n] = __builtin_amdgcn_mfma_f32_16x16x32_f16(fa[m], fb[n], acc[m][n], 0, 0, 0);
  }

  // epilogue (R6 exact)
  if (tm < 32) {
#pragma unroll
    for (int pair = 0; pair < 2; pair++) {
#pragma unroll
      for (int n = 0; n < 4; n++) {
        int col = tn * 128 + wn + n * 16 + lr;
        float bv = bg2[col];
        float s = 0.0f;
#pragma unroll
        for (int mh = 0; mh < 2; mh++) {
          int m = pair * 2 + mh;
#pragma unroll
          for (int reg = 0; reg < 4; reg++) {
            bool ok = (mh == 0) || (lg * 4 + reg < 14);
            float v = fmaxf(acc[m][n][reg] + bv, 0.0f);
            s += ok ? v : 0.0f;
          }
        }
        s += __shfl_xor(s, 16);
        s += __shfl_xor(s, 32);
        if (l < 16) {
          int g = (wm >> 5) + pair;
          outSS[(size_t)(tm * 4 + g) * 512 + col] = s;
        }
      }
    }
  } else {
#pragma unroll
    for (int m = 0; m < 4; m++) {
#pragma unroll
      for (int n = 0; n < 4; n++) {
        int col = tn * 128 + wn + n * 16 + lr;
        float bv = bg2[col];
        float s = 0.0f;
#pragma unroll
        for (int reg = 0; reg < 4; reg++) {
          float v = fmaxf(acc[m][n][reg] + bv, 0.0f);
          s += (lg < 3) ? v : 0.0f;
        }
        s += __shfl_xor(s, 16);
        s += __shfl_xor(s, 32);
        if (l < 16) {
          int h = (tm - 32) * 8 + (wm >> 4) + m;
          outSQ[(size_t)h * 512 + col] = s;
        }
      }
    }
  }
}

// ---------------------------------------------------------------------------
// Layer-3: A rows = f16(SS[ss]+SQ[gr]), B = Wf1T. Tile 128x64 (R6 geometry).
__global__ __launch_bounds__(256, 2) void gemm3_fused(
    const float* __restrict__ SS, const float* __restrict__ SQ,
    const _Float16* __restrict__ BT, const float* __restrict__ bias,
    float* __restrict__ H) {
  __shared__ __align__(16) char smem[24576];  // As[2] 16K, Bs[2] 8K

  int bid = blockIdx.x;
  { int q = gridDim.x >> 3; bid = (bid & 7) * q + (bid >> 3); }  // 128 % 8 == 0
  const int tm = bid >> 3;   // 0..15
  const int tn = bid & 7;    // 0..7
  const int t = threadIdx.x, w = t >> 6, l = t & 63;
  const int wm = (w >> 1) << 6, wn = (w & 1) << 5;
  const int lr = l & 15, lg = l >> 4;

  const int rl0 = t >> 2, c = t & 3;
  const int wchunk = c ^ ((rl0 >> 2) & 3);
  const int gr0 = tm * 128 + rl0, gr1 = gr0 + 64;
  const int ss0 = (gr0 >> 5) * 2 + (gr0 & 1);
  const int ss1 = (gr1 >> 5) * 2 + (gr1 & 1);
  const float* s0p = SS + (size_t)ss0 * 512 + c * 8;
  const float* q0p = SQ + (size_t)gr0 * 512 + c * 8;
  const float* s1p = SS + (size_t)ss1 * 512 + c * 8;
  const float* q1p = SQ + (size_t)gr1 * 512 + c * 8;

  const int kch = ((t & 3) ^ ((t >> 4) & 3)) * 8;
  const _Float16* Bg = BT + (size_t)(tn * 64 + rl0) * 512 + kch;

  _Float16* As_base = (_Float16*)smem;
  char*     Bs_base = smem + 16384;

  f32x4 acc[4][2];
#pragma unroll
  for (int m = 0; m < 4; m++)
#pragma unroll
    for (int n = 0; n < 2; n++) acc[m][n] = (f32x4){0.f, 0.f, 0.f, 0.f};
  const int rchunk = (lg ^ (lr >> 2)) * 8;

#define BUILD_S(o, a0, a1, b0, b1)                                           \
  {                                                                          \
    o[0] = (_Float16)(a0.x + b0.x); o[1] = (_Float16)(a0.y + b0.y);          \
    o[2] = (_Float16)(a0.z + b0.z); o[3] = (_Float16)(a0.w + b0.w);          \
    o[4] = (_Float16)(a1.x + b1.x); o[5] = (_Float16)(a1.y + b1.y);          \
    o[6] = (_Float16)(a1.z + b1.z); o[7] = (_Float16)(a1.w + b1.w);          \
  }

  // prologue
  gload16(Bg, Bs_base + t * 16);
  {
    float4 a0 = *(const float4*)(s0p), a1 = *(const float4*)(s0p + 4);
    float4 b0 = *(const float4*)(q0p), b1 = *(const float4*)(q0p + 4);
    float4 c0 = *(const float4*)(s1p), c1 = *(const float4*)(s1p + 4);
    float4 d0 = *(const float4*)(q1p), d1 = *(const float4*)(q1p + 4);
    f16x8 o0, o1;
    BUILD_S(o0, a0, a1, b0, b1);
    BUILD_S(o1, c0, c1, d0, d1);
    *(f16x8*)(As_base + rl0 * 32 + wchunk * 8) = o0;
    *(f16x8*)(As_base + (rl0 + 64) * 32 + wchunk * 8) = o1;
  }
  __syncthreads();

  int cur = 0;
  for (int it = 0; it < 15; ++it) {
    const int nxt = cur ^ 1;
    const int kn = (it + 1) * 32;
    gload16(Bg + kn, Bs_base + nxt * 4096 + t * 16);
    float4 a0 = *(const float4*)(s0p + kn), a1 = *(const float4*)(s0p + kn + 4);
    float4 b0 = *(const float4*)(q0p + kn), b1 = *(const float4*)(q0p + kn + 4);
    float4 c0 = *(const float4*)(s1p + kn), c1 = *(const float4*)(s1p + kn + 4);
    float4 d0 = *(const float4*)(q1p + kn), d1 = *(const float4*)(q1p + kn + 4);
    {
      _Float16* As = As_base + cur * 4096;
      _Float16* Bs = (_Float16*)(Bs_base + cur * 4096);
      f16x8 fa[4], fb[2];
#pragma unroll
      for (int m = 0; m < 4; m++)
        fa[m] = *(const f16x8*)(As + (wm + m * 16 + lr) * 32 + rchunk);
#pragma unroll
      for (int n = 0; n < 2; n++)
        fb[n] = *(const f16x8*)(Bs + (wn + n * 16 + lr) * 32 + rchunk);
#pragma unroll
      for (int m = 0; m < 4; m++)
#pragma unroll
        for (int n = 0; n < 2; n++)
          acc[m][n] = __builtin_amdgcn_mfma_f32_16x16x32_f16(fa[m], fb[n], acc[m][n], 0, 0, 0);
    }
    {
      f16x8 o0, o1;
      BUILD_S(o0, a0, a1, b0, b1);
      BUILD_S(o1, c0, c1, d0, d1);
      *(f16x8*)(As_base + nxt * 4096 + rl0 * 32 + wchunk * 8) = o0;
      *(f16x8*)(As_base + nxt * 4096 + (rl0 + 64) * 32 + wchunk * 8) = o1;
    }
    __syncthreads();
    cur = nxt;
  }
  {
    _Float16* As = As_base + cur * 4096;
    _Float16* Bs = (_Float16*)(Bs_base + cur * 4096);
    f16x8 fa[4], fb[2];
#pragma unroll
    for (int m = 0; m < 4; m++)
      fa[m] = *(const f16x8*)(As + (wm + m * 16 + lr) * 32 + rchunk);
#pragma unroll
    for (int n = 0; n < 2; n++)
      fb[n] = *(const f16x8*)(Bs + (wn + n * 16 + lr) * 32 + rchunk);
#pragma unroll
    for (int m = 0; m < 4; m++)
#pragma unroll
      for (int n = 0; n < 2; n++)
        acc[m][n] = __builtin_amdgcn_mfma_f32_16x16x32_f16(fa[m], fb[n], acc[m][n], 0, 0, 0);
  }

#pragma unroll
  for (int m = 0; m < 4; m++)
#pragma unroll
    for (int n = 0; n < 2; n++) {
      int col = tn * 64 + wn + n * 16 + lr;
#pragma unroll
      for (int reg = 0; reg < 4; reg++) {
        int row = tm * 128 + wm + m * 16 + lg * 4 + reg;
        H[(size_t)row * 512 + col] = fmaxf(acc[m][n][reg] + bias[col], 0.0f);
      }
    }
#undef BUILD_S
}

// ---------------------------------------------------------------------------
// logits: one wave per row (proven)
__global__ void final_dot(const float* __restrict__ h, const float* __restrict__ Wf2,
                          const float* __restrict__ bf2, float* __restrict__ out) {
  int row = blockIdx.x * 4 + (threadIdx.x >> 6);
  int l = threadIdx.x & 63;
  const float4* hp = (const float4*)(h + (size_t)row * 512);
  const float4* wp = (const float4*)Wf2;
  float s = 0.0f;
#pragma unroll
  for (int i = 0; i < 2; i++) {
    float4 a = hp[l + 64 * i];
    float4 b = wp[l + 64 * i];
    s += a.x * b.x + a.y * b.y + a.z * b.z + a.w * b.w;
  }
#pragma unroll
  for (int off = 32; off; off >>= 1) s += __shfl_down(s, off, 64);
  if (l == 0) out[row] = s + bf2[0];
}

// ---------------------------------------------------------------------------
extern "C" void kernel_launch(void* const* d_in, const int* in_sizes, int n_in,
                              void* d_out, int out_size, void* d_ws, size_t ws_size,
                              hipStream_t stream) {
  const float* xs  = (const float*)d_in[0];
  const float* xq  = (const float*)d_in[1];
  const float* Wg1 = (const float*)d_in[2];
  const float* bg1 = (const float*)d_in[3];
  const float* Wg2 = (const float*)d_in[4];
  const float* bg2 = (const float*)d_in[5];
  const float* Wf1 = (const float*)d_in[6];
  const float* bf1 = (const float*)d_in[7];
  const float* Wf2 = (const float*)d_in[8];
  const float* bf2 = (const float*)d_in[9];
  float* out = (float*)d_out;

  char* ws = (char*)d_ws;
  _Float16* Wg1T = (_Float16*)(ws);             // 1,048,576
  _Float16* Wg2T = (_Float16*)(ws + 1048576);   //   524,288
  _Float16* Wf1T = (_Float16*)(ws + 1572864);   //   524,288
  _Float16* UVh  = (_Float16*)(ws + 2097152);   // 3,670,016
  float*    SSs  = (float*)(ws + 5767168);      //   262,144
  float*    SQs  = (float*)(ws + 6029312);      // 4,194,304
  float*    Hf   = (float*)(ws + 10223616);     // 4,194,304

  convert_t<<<512, 256, 0, stream>>>(Wg1, Wg2, Wf1, Wg1T, Wg2T, Wf1T);
  gemm1_fused<<<224, 256, 0, stream>>>(xs, xq, Wg1T, bg1, UVh);
  gemm2_fused<<<1152, 256, 0, stream>>>(UVh, Wg2T, bg2, SSs, SQs);
  gemm3_fused<<<128, 256, 0, stream>>>(SSs, SQs, Wf1T, bf1, Hf);
  final_dot<<<512, 256, 0, stream>>>(Hf, Wf2, bf2, out);
}